// Round 5
// baseline (984.844 us; speedup 1.0000x reference)
//
#include <hip/hip_runtime.h>
#include <hip/hip_bf16.h>
#include <cmath>

typedef __hip_bfloat16 bf16;
typedef __bf16 bf16x8 __attribute__((ext_vector_type(8)));
typedef float f32x4 __attribute__((ext_vector_type(4)));

typedef __attribute__((address_space(1))) void void_g;
typedef __attribute__((address_space(3))) void void_l;

#define SEQ 2048
#define DMODEL 1024
#define NHEAD 16
#define HDIM 64
#define DFF 4096
#define WINDOW 128
#define LN_EPS 1e-5f

__device__ __forceinline__ void gl_lds16(const bf16* g, bf16* l) {
    __builtin_amdgcn_global_load_lds((void_g*)(g), (void_l*)(l), 16, 0, 0);
}

__device__ __forceinline__ bf16x8 cvt8(float4 a, float4 b) {
    bf16x8 w;
    w[0] = (__bf16)a.x; w[1] = (__bf16)a.y; w[2] = (__bf16)a.z; w[3] = (__bf16)a.w;
    w[4] = (__bf16)b.x; w[5] = (__bf16)b.y; w[6] = (__bf16)b.z; w[7] = (__bf16)b.w;
    return w;
}

// ---------------- zero f32 buffer ----------------
__global__ __launch_bounds__(256)
void zero_f32(float4* __restrict__ p) {
    p[blockIdx.x * 256 + threadIdx.x] = (float4){0.f, 0.f, 0.f, 0.f};
}

// ---------------- positional encoding add: f32 in -> bf16 out ----------------
__global__ __launch_bounds__(256)
void add_pe(const float* __restrict__ X, bf16* __restrict__ x) {
    int idx = blockIdx.x * 256 + threadIdx.x;
    int s = idx >> 10, d = idx & 1023;
    float i2 = (float)(d & ~1);
    float div = expf(i2 * (-9.210340371976184f / 1024.0f));
    float ang = (float)s * div;
    float pe = (d & 1) ? cosf(ang) : sinf(ang);
    x[idx] = (bf16)(X[idx] + pe);
}

// ---------------- per-layer weight f32 -> bf16 conversion ----------------
// dst layout (bf16 elems): qkv[3072x1024] | wo[1024x1024] | w1[4096x1024] | w2[1024x4096]
__global__ __launch_bounds__(256)
void cvt_w_layer(const float* __restrict__ wqkv, const float* __restrict__ wo,
                 const float* __restrict__ w1, const float* __restrict__ w2,
                 bf16* __restrict__ dst)
{
    int i = blockIdx.x * 256 + threadIdx.x;   // 8-elem group id, [0, 1572864)
    const float* src; size_t so;
    if (i < 393216)       { src = wqkv; so = (size_t)i * 8; }
    else if (i < 524288)  { src = wo;   so = (size_t)(i - 393216) * 8; }
    else if (i < 1048576) { src = w1;   so = (size_t)(i - 524288) * 8; }
    else                  { src = w2;   so = (size_t)(i - 1048576) * 8; }
    float4 a = *(const float4*)(src + so);
    float4 b = *(const float4*)(src + so + 4);
    *(bf16x8*)(dst + (size_t)i * 8) = cvt8(a, b);
}

// ======================= minimal-2-phase GEMM core: 256M x 128N, BK=64 =======================
// 512 threads = 8 waves (4M x 2N), each wave computes 64x64 (acc[4][4]).
// Verified "T3-minimum + T4" structure (m230/m248: 655-682 TF at this shape):
//   per K-step: {issue 6 gl_lds for t+2 | 16 ds_read_b128 for step t |
//                32 MFMA (setprio-wrapped) | s_waitcnt vmcnt(6) | raw s_barrier}
// ONE barrier per K-step; vmcnt NEVER 0 mid-loop (counted: 6 loads for t+2 stay
// in flight across the barrier; the wait retires step t+1's 6 loads, whose
// latency was hidden under a full K-step of compute). Triple-buffered LDS
// (144 KiB): buffer read at t is rotated to the write target at t+1, protected
// by the end-of-step barrier. ds_read->MFMA ordering: plain C++ loads, the
// compiler emits fine-grained partial lgkmcnt waits (its strength per m97 asm).
// LDS layout per buffer, per ks-half (32 k-elems): [rows][32], chunk-XOR
// swizzle kch=(c&3)^(row&3); source address pre-swizzled so LDS stays linear.
// Frag read: half ks: base + ks*ROWS*32 + row*32 + (quad^(r&3))*8.

#define G8_PROLOGUE(Adecl, Wdecl)                                                \
    __shared__ __align__(16) bf16 AS[3][256 * 64];                               \
    __shared__ __align__(16) bf16 BS[3][128 * 64];                               \
    const int tid  = threadIdx.x;                                                \
    const int lane = tid & 63;                                                   \
    const int wave = tid >> 6;                                                   \
    const int wm = wave >> 1, wn = wave & 1;                                     \
    const int r = lane & 15, quad = lane >> 4;                                   \
    const int rc = (quad ^ (r & 3)) * 8;                                         \
    f32x4 acc[4][4];                                                             \
    _Pragma("unroll")                                                            \
    for (int i = 0; i < 4; ++i)                                                  \
        _Pragma("unroll")                                                        \
        for (int j = 0; j < 4; ++j) acc[i][j] = (f32x4){0.f, 0.f, 0.f, 0.f};     \
    const bf16* ApA[4]; const bf16* ApB[2];                                      \
    _Pragma("unroll")                                                            \
    for (int i = 0; i < 4; ++i) {                                                \
        int c = tid + 512 * i;                                                   \
        int ks = c >> 10, row = (c >> 2) & 255, kch = (c & 3) ^ (row & 3);       \
        ApA[i] = (Adecl) + (size_t)(m0 + row) * K + ks * 32 + kch * 8;           \
    }                                                                            \
    _Pragma("unroll")                                                            \
    for (int i = 0; i < 2; ++i) {                                                \
        int c = tid + 512 * i;                                                   \
        int ks = c >> 9, row = (c >> 2) & 127, kch = (c & 3) ^ (row & 3);        \
        ApB[i] = (Wdecl) + (size_t)(n0 + row) * K + ks * 32 + kch * 8;           \
    }

#define G8_STAGE(koff, Adst, Bdst)                                               \
    _Pragma("unroll")                                                            \
    for (int i = 0; i < 4; ++i)                                                  \
        gl_lds16(ApA[i] + (koff), (Adst) + (size_t)(tid + 512 * i) * 8);         \
    _Pragma("unroll")                                                            \
    for (int i = 0; i < 2; ++i)                                                  \
        gl_lds16(ApB[i] + (koff), (Bdst) + (size_t)(tid + 512 * i) * 8);

#define G8_KLOOP(Klim)                                                           \
    const int nit = (Klim) / 64;                                                 \
    bf16 *A_c = &AS[0][0], *A_n = &AS[1][0], *A_f = &AS[2][0];                   \
    bf16 *B_c = &BS[0][0], *B_n = &BS[1][0], *B_f = &BS[2][0];                   \
    G8_STAGE(0, A_c, B_c)                                                        \
    if (nit > 1) {                                                               \
        G8_STAGE(64, A_n, B_n)                                                   \
        asm volatile("s_waitcnt vmcnt(6)" ::: "memory");                         \
    } else {                                                                     \
        asm volatile("s_waitcnt vmcnt(0)" ::: "memory");                         \
    }                                                                            \
    __builtin_amdgcn_s_barrier();                                                \
    for (int t = 0; t < nit; ++t) {                                              \
        const bool stg = (t + 2 < nit);                                          \
        if (stg) { G8_STAGE((t + 2) * 64, A_f, B_f) }                            \
        bf16x8 av[4][2], bv[4][2];                                               \
        _Pragma("unroll")                                                        \
        for (int mf = 0; mf < 4; ++mf)                                           \
            _Pragma("unroll")                                                    \
            for (int kk = 0; kk < 2; ++kk)                                       \
                av[mf][kk] = *(const bf16x8*)(A_c + kk * 8192 +                  \
                              (wm * 64 + mf * 16 + r) * 32 + rc);                \
        _Pragma("unroll")                                                        \
        for (int nf = 0; nf < 4; ++nf)                                           \
            _Pragma("unroll")                                                    \
            for (int kk = 0; kk < 2; ++kk)                                       \
                bv[nf][kk] = *(const bf16x8*)(B_c + kk * 4096 +                  \
                              (wn * 64 + nf * 16 + r) * 32 + rc);                \
        __builtin_amdgcn_s_setprio(1);                                           \
        _Pragma("unroll")                                                        \
        for (int mf = 0; mf < 4; ++mf)                                           \
            _Pragma("unroll")                                                    \
            for (int nf = 0; nf < 4; ++nf)                                       \
                _Pragma("unroll")                                                \
                for (int kk = 0; kk < 2; ++kk)                                   \
                    acc[mf][nf] = __builtin_amdgcn_mfma_f32_16x16x32_bf16(       \
                        av[mf][kk], bv[nf][kk], acc[mf][nf], 0, 0, 0);           \
        __builtin_amdgcn_s_setprio(0);                                           \
        if (stg) asm volatile("s_waitcnt vmcnt(6)" ::: "memory");                \
        else     asm volatile("s_waitcnt vmcnt(0)" ::: "memory");                \
        __builtin_amdgcn_s_barrier();                                            \
        bf16* tA = A_c; A_c = A_n; A_n = A_f; A_f = tA;                          \
        bf16* tB = B_c; B_c = B_n; B_n = B_f; B_f = tB;                          \
    }

// ---------------- direct GEMM: C[M,N] = A[M,K]*W[N,K]^T + bias, bf16 W ----------------
template<int ACT>
__global__ __launch_bounds__(512)
void gemm8_bt(const bf16* __restrict__ A, const bf16* __restrict__ W,
              const float* __restrict__ bias, bf16* __restrict__ C,
              int M, int N, int K)
{
    const int m0 = blockIdx.y * 256, n0 = blockIdx.x * 128;
    G8_PROLOGUE(A, W)
    G8_KLOOP(K)
#pragma unroll
    for (int nt = 0; nt < 4; ++nt) {
        int n = n0 + wn * 64 + nt * 16 + r;
        float bv = bias[n];
#pragma unroll
        for (int mt = 0; mt < 4; ++mt) {
#pragma unroll
            for (int e = 0; e < 4; ++e) {
                int m = m0 + wm * 64 + mt * 16 + quad * 4 + e;
                float v = acc[mt][nt][e] + bv;
                if (ACT == 1) v = fmaxf(v, 0.f);
                C[(size_t)m * N + n] = (bf16)v;
            }
        }
    }
}

// ---------------- split-K GEMM: Cacc += A*W^T (f32 atomic), bf16 W ----------------
// Row stride = K (full); K-loop runs over Kc = K/SPLIT.
template<int SPLIT>
__global__ __launch_bounds__(512)
void gemm8_splitk(const bf16* __restrict__ A, const bf16* __restrict__ Wfull,
                  float* __restrict__ Cacc, int M, int N, int K)
{
    const int m0 = blockIdx.y * 256, n0 = blockIdx.x * 128;
    const int Kc = K / SPLIT;
    const bf16* Ab = A + (size_t)blockIdx.z * Kc;
    const bf16* W = Wfull + (size_t)blockIdx.z * Kc;
    G8_PROLOGUE(Ab, W)
    G8_KLOOP(Kc)
#pragma unroll
    for (int nt = 0; nt < 4; ++nt) {
        int n = n0 + wn * 64 + nt * 16 + r;
#pragma unroll
        for (int mt = 0; mt < 4; ++mt) {
#pragma unroll
            for (int e = 0; e < 4; ++e) {
                int m = m0 + wm * 64 + mt * 16 + quad * 4 + e;
                atomicAdd(&Cacc[(size_t)m * N + n], acc[mt][nt][e]);
            }
        }
    }
}

// ---------------- V transpose: qkv v-part [s][h*64+d] -> Vt[h*64+d][s] ----------------
__global__ __launch_bounds__(256)
void transpose_v(const bf16* __restrict__ qkv, bf16* __restrict__ Vt)
{
    __shared__ __bf16 t[64][66];
    const int s0 = blockIdx.x * 64, dm0 = blockIdx.y * 64;
    const int tid = threadIdx.x;
    const int sl = tid >> 2, dc = (tid & 3) * 16;
    const bf16* src = qkv + (size_t)(s0 + sl) * 3072 + 2048 + dm0 + dc;
    bf16x8 v0 = *(const bf16x8*)(src);
    bf16x8 v1 = *(const bf16x8*)(src + 8);
#pragma unroll
    for (int j = 0; j < 8; ++j) { t[sl][dc + j] = v0[j]; t[sl][dc + 8 + j] = v1[j]; }
    __syncthreads();
    const int dl = tid >> 2, sc = (tid & 3) * 16;
    bf16x8 o0, o1;
#pragma unroll
    for (int j = 0; j < 8; ++j) { o0[j] = t[sc + j][dl]; o1[j] = t[sc + 8 + j][dl]; }
    bf16* dst = Vt + (size_t)(dm0 + dl) * SEQ + s0 + sc;
    *(bf16x8*)(dst) = o0;
    *(bf16x8*)(dst + 8) = o1;
}

// ---------------- banded flash attention with MFMA ----------------
__global__ __launch_bounds__(256)
void attn_mfma(const bf16* __restrict__ qkv, const bf16* __restrict__ Vt,
               bf16* __restrict__ o)
{
    __shared__ __align__(16) __bf16 Plds[4][16 * 40];
    const int tid = threadIdx.x, lane = tid & 63, w = tid >> 6;
    const int h = blockIdx.x & 15;
    const int qw = (blockIdx.x >> 4) * 64 + w * 16;
    const int r = lane & 15, quad = lane >> 4;
    __bf16* P = Plds[w];

    bf16x8 qa[2];
    {
        const bf16* qrow = qkv + (size_t)(qw + r) * 3072 + h * 64 + quad * 8;
#pragma unroll
        for (int c = 0; c < 2; ++c) {
            bf16x8 t = *(const bf16x8*)(qrow + c * 32);
#pragma unroll
            for (int j = 0; j < 8; ++j) qa[c][j] = (__bf16)((float)t[j] * 0.125f);
        }
    }

    bf16x8 ones;
#pragma unroll
    for (int j = 0; j < 8; ++j) ones[j] = (__bf16)1.0f;

    f32x4 acc[4];
#pragma unroll
    for (int d = 0; d < 4; ++d) acc[d] = (f32x4){0.f, 0.f, 0.f, 0.f};
    float m_run[4], l_run[4];
#pragma unroll
    for (int e = 0; e < 4; ++e) { m_run[e] = -1e30f; l_run[e] = 0.f; }

    int jmin = qw - (WINDOW - 1); if (jmin < 0) jmin = 0;
    int jmax = qw + 15 + (WINDOW - 1); if (jmax > SEQ - 1) jmax = SEQ - 1;

    for (int kt = jmin & ~31; kt <= jmax; kt += 32) {
        f32x4 S[2];
#pragma unroll
        for (int c = 0; c < 2; ++c) {
            const bf16* krow = qkv + (size_t)(kt + 16 * c + r) * 3072 + 1024 + h * 64 + quad * 8;
            bf16x8 kb0 = *(const bf16x8*)(krow);
            bf16x8 kb1 = *(const bf16x8*)(krow + 32);
            f32x4 s = (f32x4){0.f, 0.f, 0.f, 0.f};
            s = __builtin_amdgcn_mfma_f32_16x16x32_bf16(qa[0], kb0, s, 0, 0, 0);
            s = __builtin_amdgcn_mfma_f32_16x16x32_bf16(qa[1], kb1, s, 0, 0, 0);
            S[c] = s;
        }
#pragma unroll
        for (int c = 0; c < 2; ++c)
#pragma unroll
            for (int e = 0; e < 4; ++e) {
                int j = kt + 16 * c + r;
                int i = qw + quad * 4 + e;
                bool valid = (unsigned)(j - i + (WINDOW - 1)) <= (unsigned)(2 * WINDOW - 2);
                S[c][e] = valid ? S[c][e] : -1e30f;
            }
        float alpha[4], mnew[4];
#pragma unroll
        for (int e = 0; e < 4; ++e) {
            float v = fmaxf(S[0][e], S[1][e]);
#pragma unroll
            for (int off = 1; off <= 8; off <<= 1) v = fmaxf(v, __shfl_xor(v, off, 64));
            mnew[e] = fmaxf(m_run[e], v);
            alpha[e] = __expf(m_run[e] - mnew[e]);
            m_run[e] = mnew[e];
        }
#pragma unroll
        for (int c = 0; c < 2; ++c)
#pragma unroll
            for (int e = 0; e < 4; ++e) {
                float p = __expf(S[c][e] - mnew[e]);
                p = (S[c][e] <= -1e29f) ? 0.f : p;
                P[(quad * 4 + e) * 40 + 16 * c + r] = (__bf16)p;
            }
        bf16x8 pa = *(const bf16x8*)(P + r * 40 + quad * 8);
#pragma unroll
        for (int d = 0; d < 4; ++d)
#pragma unroll
            for (int e = 0; e < 4; ++e) acc[d][e] *= alpha[e];
        f32x4 ls = (f32x4){0.f, 0.f, 0.f, 0.f};
        ls = __builtin_amdgcn_mfma_f32_16x16x32_bf16(pa, ones, ls, 0, 0, 0);
#pragma unroll
        for (int e = 0; e < 4; ++e) l_run[e] = l_run[e] * alpha[e] + ls[e];
#pragma unroll
        for (int d = 0; d < 4; ++d) {
            const bf16* vrow = Vt + (size_t)(h * 64 + 16 * d + r) * SEQ + kt + quad * 8;
            bf16x8 vb = *(const bf16x8*)(vrow);
            acc[d] = __builtin_amdgcn_mfma_f32_16x16x32_bf16(pa, vb, acc[d], 0, 0, 0);
        }
    }

#pragma unroll
    for (int d = 0; d < 4; ++d)
#pragma unroll
        for (int e = 0; e < 4; ++e) {
            int i = qw + quad * 4 + e;
            o[(size_t)i * DMODEL + h * 64 + 16 * d + r] = (bf16)(acc[d][e] / l_run[e]);
        }
}

// ---------------- residual + layernorm, delta = f32 acc + f32 bias ----------------
__global__ __launch_bounds__(256)
void ln_residual_f32(bf16* __restrict__ x, const float* __restrict__ accd,
                     const float* __restrict__ bias,
                     const float* __restrict__ gamma, const float* __restrict__ beta)
{
    const int s = blockIdx.x, tid = threadIdx.x;
    const int lane = tid & 63, wave = tid >> 6;
    __shared__ float red[8];
    float v[4];
    float sum = 0.f;
#pragma unroll
    for (int i = 0; i < 4; ++i) {
        int d = i * 256 + tid;
        v[i] = (float)x[(size_t)s * 1024 + d] + accd[(size_t)s * 1024 + d] + bias[d];
        sum += v[i];
    }
#pragma unroll
    for (int off = 32; off; off >>= 1) sum += __shfl_xor(sum, off, 64);
    if (lane == 0) red[wave] = sum;
    __syncthreads();
    float mu = (red[0] + red[1] + red[2] + red[3]) * (1.f / 1024.f);
    float sq = 0.f;
#pragma unroll
    for (int i = 0; i < 4; ++i) { float t = v[i] - mu; sq += t * t; }
#pragma unroll
    for (int off = 32; off; off >>= 1) sq += __shfl_xor(sq, off, 64);
    if (lane == 0) red[wave + 4] = sq;
    __syncthreads();
    float var = (red[4] + red[5] + red[6] + red[7]) * (1.f / 1024.f);
    float inv = rsqrtf(var + LN_EPS);
#pragma unroll
    for (int i = 0; i < 4; ++i) {
        int d = i * 256 + tid;
        x[(size_t)s * 1024 + d] = (bf16)((v[i] - mu) * inv * gamma[d] + beta[d]);
    }
}

// ---------------- decoder: logits + log_softmax ----------------
__global__ __launch_bounds__(256)
void decoder(const bf16* __restrict__ x, const float* __restrict__ Wdec,
             const float* __restrict__ bdec, float* __restrict__ out)
{
    const int s = blockIdx.x * 4 + (threadIdx.x >> 6);
    const int lane = threadIdx.x & 63;
    float a0 = 0.f, a1 = 0.f, a2 = 0.f;
    for (int d = lane; d < 1024; d += 64) {
        float xv = (float)x[(size_t)s * 1024 + d];
        a0 += xv * Wdec[d];
        a1 += xv * Wdec[1024 + d];
        a2 += xv * Wdec[2048 + d];
    }
#pragma unroll
    for (int off = 32; off; off >>= 1) {
        a0 += __shfl_xor(a0, off, 64);
        a1 += __shfl_xor(a1, off, 64);
        a2 += __shfl_xor(a2, off, 64);
    }
    if (lane == 0) {
        float z0 = a0 + bdec[0];
        float z1 = a1 + bdec[1];
        float z2 = a2 + bdec[2];
        float mx = fmaxf(z0, fmaxf(z1, z2));
        float lse = mx + logf(__expf(z0 - mx) + __expf(z1 - mx) + __expf(z2 - mx));
        out[s * 3 + 0] = z0 - lse;
        out[s * 3 + 1] = z1 - lse;
        out[s * 3 + 2] = z2 - lse;
    }
}

extern "C" void kernel_launch(void* const* d_in, const int* in_sizes, int n_in,
                              void* d_out, int out_size, void* d_ws, size_t ws_size,
                              hipStream_t stream)
{
    const float* X    = (const float*)d_in[0];
    const float* Wqkv = (const float*)d_in[1];
    const float* bqkv = (const float*)d_in[2];
    const float* Wo   = (const float*)d_in[3];
    const float* bo   = (const float*)d_in[4];
    const float* ln1g = (const float*)d_in[5];
    const float* ln1b = (const float*)d_in[6];
    const float* W1   = (const float*)d_in[7];
    const float* b1   = (const float*)d_in[8];
    const float* W2   = (const float*)d_in[9];
    const float* b2   = (const float*)d_in[10];
    const float* ln2g = (const float*)d_in[11];
    const float* ln2b = (const float*)d_in[12];
    const float* Wdec = (const float*)d_in[13];
    const float* bdec = (const float*)d_in[14];

    // workspace (bf16 elems):
    //   x[2M] | buf[8M]=qkv6M/ao2M (reused as h) | Vt[2M] | accf 2M f32 (4M-equiv)
    //   | Wb[12.583M] per-layer bf16 weights
    bf16* ws   = (bf16*)d_ws;
    bf16* x    = ws;                                  // 2M
    bf16* buf  = x   + (size_t)SEQ * DMODEL;          // 8M
    bf16* qkv  = buf;
    bf16* ao   = buf + (size_t)SEQ * 3 * DMODEL;
    bf16* h    = buf;
    bf16* Vt   = buf + (size_t)SEQ * DFF;             // 2M
    float* accf = (float*)(Vt + (size_t)SEQ * DMODEL);    // 2M f32 (8 MB)
    bf16* Wb   = (bf16*)(accf + (size_t)SEQ * DMODEL);    // 12.583M bf16
    bf16* WoB  = Wb + 3145728;
    bf16* W1B  = Wb + 4194304;
    bf16* W2B  = Wb + 8388608;

    add_pe<<<(SEQ * DMODEL) / 256, 256, 0, stream>>>(X, x);

    for (int l = 0; l < 4; ++l) {
        // convert this layer's weights f32 -> bf16 (contiguous Wb)
        cvt_w_layer<<<6144, 256, 0, stream>>>(
            Wqkv + (size_t)l * 3145728, Wo + (size_t)l * 1048576,
            W1 + (size_t)l * 4194304,  W2 + (size_t)l * 4194304, Wb);
        // QKV projection
        gemm8_bt<0><<<dim3(3072 / 128, SEQ / 256), 512, 0, stream>>>(
            x, Wb, bqkv + l * 3072, qkv, SEQ, 3072, 1024);
        // banded flash attention
        transpose_v<<<dim3(SEQ / 64, DMODEL / 64), 256, 0, stream>>>(qkv, Vt);
        attn_mfma<<<(SEQ / 64) * NHEAD, 256, 0, stream>>>(qkv, Vt, ao);
        // O projection (split-K=4, f32 atomic; bias folded into LN)
        zero_f32<<<(SEQ * DMODEL / 4) / 256, 256, 0, stream>>>((float4*)accf);
        gemm8_splitk<4><<<dim3(1024 / 128, SEQ / 256, 4), 512, 0, stream>>>(
            ao, WoB, accf, SEQ, 1024, 1024);
        ln_residual_f32<<<SEQ, 256, 0, stream>>>(x, accf, bo + l * 1024,
                                                 ln1g + l * 1024, ln1b + l * 1024);
        // FF1 (relu, direct) — h overwrites qkv/ao region
        gemm8_bt<1><<<dim3(4096 / 128, SEQ / 256), 512, 0, stream>>>(
            x, W1B, b1 + l * 4096, h, SEQ, 4096, 1024);
        // FF2 (split-K=4, f32 atomic; bias folded into LN)
        zero_f32<<<(SEQ * DMODEL / 4) / 256, 256, 0, stream>>>((float4*)accf);
        gemm8_splitk<4><<<dim3(1024 / 128, SEQ / 256, 4), 512, 0, stream>>>(
            h, W2B, accf, SEQ, 1024, 4096);
        ln_residual_f32<<<SEQ, 256, 0, stream>>>(x, accf, b2 + l * 1024,
                                                 ln2g + l * 1024, ln2b + l * 1024);
    }

    decoder<<<SEQ / 4, 256, 0, stream>>>(x, Wdec, bdec, (float*)d_out);
}

// Round 6
// 824.986 us; speedup vs baseline: 1.1938x; 1.1938x over previous
//
#include <hip/hip_runtime.h>
#include <hip/hip_bf16.h>
#include <cmath>

typedef __hip_bfloat16 bf16;
typedef __bf16 bf16x8 __attribute__((ext_vector_type(8)));
typedef float f32x4 __attribute__((ext_vector_type(4)));

typedef __attribute__((address_space(1))) void void_g;
typedef __attribute__((address_space(3))) void void_l;

#define SEQ 2048
#define DMODEL 1024
#define NHEAD 16
#define HDIM 64
#define DFF 4096
#define WINDOW 128
#define LN_EPS 1e-5f

__device__ __forceinline__ void gl_lds16(const bf16* g, bf16* l) {
    __builtin_amdgcn_global_load_lds((void_g*)(g), (void_l*)(l), 16, 0, 0);
}

__device__ __forceinline__ bf16x8 cvt8(float4 a, float4 b) {
    bf16x8 w;
    w[0] = (__bf16)a.x; w[1] = (__bf16)a.y; w[2] = (__bf16)a.z; w[3] = (__bf16)a.w;
    w[4] = (__bf16)b.x; w[5] = (__bf16)b.y; w[6] = (__bf16)b.z; w[7] = (__bf16)b.w;
    return w;
}

// ---------------- positional encoding add: f32 in -> bf16 out ----------------
__global__ __launch_bounds__(256)
void add_pe(const float* __restrict__ X, bf16* __restrict__ x) {
    int idx = blockIdx.x * 256 + threadIdx.x;
    int s = idx >> 10, d = idx & 1023;
    float i2 = (float)(d & ~1);
    float div = expf(i2 * (-9.210340371976184f / 1024.0f));
    float ang = (float)s * div;
    float pe = (d & 1) ? cosf(ang) : sinf(ang);
    x[idx] = (bf16)(X[idx] + pe);
}

// ---------------- per-layer weight f32 -> bf16 conversion ----------------
// dst layout (bf16 elems): qkv[3072x1024] | wo[1024x1024] | w1[4096x1024] | w2[1024x4096]
__global__ __launch_bounds__(256)
void cvt_w_layer(const float* __restrict__ wqkv, const float* __restrict__ wo,
                 const float* __restrict__ w1, const float* __restrict__ w2,
                 bf16* __restrict__ dst)
{
    int i = blockIdx.x * 256 + threadIdx.x;   // 8-elem group id, [0, 1572864)
    const float* src; size_t so;
    if (i < 393216)       { src = wqkv; so = (size_t)i * 8; }
    else if (i < 524288)  { src = wo;   so = (size_t)(i - 393216) * 8; }
    else if (i < 1048576) { src = w1;   so = (size_t)(i - 524288) * 8; }
    else                  { src = w2;   so = (size_t)(i - 1048576) * 8; }
    float4 a = *(const float4*)(src + so);
    float4 b = *(const float4*)(src + so + 4);
    *(bf16x8*)(dst + (size_t)i * 8) = cvt8(a, b);
}

// ======================= minimal-2-phase GEMM core: 256M x 128N, BK=64 =======================
// 512 threads = 8 waves (4M x 2N), each wave computes 64x64 (acc[4][4]).
// Per K-step: {issue 6 gl_lds for t+2 | 16 ds_read_b128 for step t |
//              32 MFMA (setprio-wrapped) | s_waitcnt vmcnt(6) | raw s_barrier}
// ONE barrier per K-step; vmcnt NEVER 0 mid-loop. Triple-buffered LDS (144 KiB).
// LDS layout per buffer, per ks-half (32 k-elems): [rows][32], chunk-XOR
// swizzle kch=(c&3)^(row&3); source address pre-swizzled so LDS stays linear.
// Frag read: half ks: base + ks*ROWS*32 + row*32 + (quad^(r&3))*8.
// Block mapping: T1 XCD swizzle -- original bid (round-robin to XCDs) remapped
// so XCD k computes a contiguous tile range (grids all divisible by 8).

#define G8_PROLOGUE(Adecl, Wdecl)                                                \
    __shared__ __align__(16) bf16 AS[3][256 * 64];                               \
    __shared__ __align__(16) bf16 BS[3][128 * 64];                               \
    const int tid  = threadIdx.x;                                                \
    const int lane = tid & 63;                                                   \
    const int wave = tid >> 6;                                                   \
    const int wm = wave >> 1, wn = wave & 1;                                     \
    const int r = lane & 15, quad = lane >> 4;                                   \
    const int rc = (quad ^ (r & 3)) * 8;                                         \
    f32x4 acc[4][4];                                                             \
    _Pragma("unroll")                                                            \
    for (int i = 0; i < 4; ++i)                                                  \
        _Pragma("unroll")                                                        \
        for (int j = 0; j < 4; ++j) acc[i][j] = (f32x4){0.f, 0.f, 0.f, 0.f};     \
    const bf16* ApA[4]; const bf16* ApB[2];                                      \
    _Pragma("unroll")                                                            \
    for (int i = 0; i < 4; ++i) {                                                \
        int c = tid + 512 * i;                                                   \
        int ks = c >> 10, row = (c >> 2) & 255, kch = (c & 3) ^ (row & 3);       \
        ApA[i] = (Adecl) + (size_t)(m0 + row) * K + ks * 32 + kch * 8;           \
    }                                                                            \
    _Pragma("unroll")                                                            \
    for (int i = 0; i < 2; ++i) {                                                \
        int c = tid + 512 * i;                                                   \
        int ks = c >> 9, row = (c >> 2) & 127, kch = (c & 3) ^ (row & 3);        \
        ApB[i] = (Wdecl) + (size_t)(n0 + row) * K + ks * 32 + kch * 8;           \
    }

#define G8_STAGE(koff, Adst, Bdst)                                               \
    _Pragma("unroll")                                                            \
    for (int i = 0; i < 4; ++i)                                                  \
        gl_lds16(ApA[i] + (koff), (Adst) + (size_t)(tid + 512 * i) * 8);         \
    _Pragma("unroll")                                                            \
    for (int i = 0; i < 2; ++i)                                                  \
        gl_lds16(ApB[i] + (koff), (Bdst) + (size_t)(tid + 512 * i) * 8);

#define G8_KLOOP(Klim)                                                           \
    const int nit = (Klim) / 64;                                                 \
    bf16 *A_c = &AS[0][0], *A_n = &AS[1][0], *A_f = &AS[2][0];                   \
    bf16 *B_c = &BS[0][0], *B_n = &BS[1][0], *B_f = &BS[2][0];                   \
    G8_STAGE(0, A_c, B_c)                                                        \
    if (nit > 1) {                                                               \
        G8_STAGE(64, A_n, B_n)                                                   \
        asm volatile("s_waitcnt vmcnt(6)" ::: "memory");                         \
    } else {                                                                     \
        asm volatile("s_waitcnt vmcnt(0)" ::: "memory");                         \
    }                                                                            \
    __builtin_amdgcn_s_barrier();                                                \
    for (int t = 0; t < nit; ++t) {                                              \
        const bool stg = (t + 2 < nit);                                          \
        if (stg) { G8_STAGE((t + 2) * 64, A_f, B_f) }                            \
        bf16x8 av[4][2], bv[4][2];                                               \
        _Pragma("unroll")                                                        \
        for (int mf = 0; mf < 4; ++mf)                                           \
            _Pragma("unroll")                                                    \
            for (int kk = 0; kk < 2; ++kk)                                       \
                av[mf][kk] = *(const bf16x8*)(A_c + kk * 8192 +                  \
                              (wm * 64 + mf * 16 + r) * 32 + rc);                \
        _Pragma("unroll")                                                        \
        for (int nf = 0; nf < 4; ++nf)                                           \
            _Pragma("unroll")                                                    \
            for (int kk = 0; kk < 2; ++kk)                                       \
                bv[nf][kk] = *(const bf16x8*)(B_c + kk * 4096 +                  \
                              (wn * 64 + nf * 16 + r) * 32 + rc);                \
        __builtin_amdgcn_s_setprio(1);                                           \
        _Pragma("unroll")                                                        \
        for (int mf = 0; mf < 4; ++mf)                                           \
            _Pragma("unroll")                                                    \
            for (int nf = 0; nf < 4; ++nf)                                       \
                _Pragma("unroll")                                                \
                for (int kk = 0; kk < 2; ++kk)                                   \
                    acc[mf][nf] = __builtin_amdgcn_mfma_f32_16x16x32_bf16(       \
                        av[mf][kk], bv[nf][kk], acc[mf][nf], 0, 0, 0);           \
        __builtin_amdgcn_s_setprio(0);                                           \
        if (stg) asm volatile("s_waitcnt vmcnt(6)" ::: "memory");                \
        else     asm volatile("s_waitcnt vmcnt(0)" ::: "memory");                \
        __builtin_amdgcn_s_barrier();                                            \
        bf16* tA = A_c; A_c = A_n; A_n = A_f; A_f = tA;                          \
        bf16* tB = B_c; B_c = B_n; B_n = B_f; B_f = tB;                          \
    }

// T1 XCD-aware swizzle of the 2D grid (nwg must be divisible by 8 -- all ours are).
#define G8_SWZ_TILE()                                                            \
    const int gx = gridDim.x, gy = gridDim.y;                                    \
    const int bid = blockIdx.y * gx + blockIdx.x;                                \
    const int cpx = (gx * gy) >> 3;                                              \
    const int swz = (bid & 7) * cpx + (bid >> 3);                                \
    const int m0 = (swz / gx) * 256, n0 = (swz % gx) * 128;

// ---------------- direct GEMM: C[M,N] = A[M,K]*W[N,K]^T + bias, bf16 W ----------------
template<int ACT>
__global__ __launch_bounds__(512)
void gemm8_bt(const bf16* __restrict__ A, const bf16* __restrict__ W,
              const float* __restrict__ bias, bf16* __restrict__ C,
              int M, int N, int K)
{
    G8_SWZ_TILE()
    G8_PROLOGUE(A, W)
    G8_KLOOP(K)
#pragma unroll
    for (int nt = 0; nt < 4; ++nt) {
        int n = n0 + wn * 64 + nt * 16 + r;
        float bv = bias[n];
#pragma unroll
        for (int mt = 0; mt < 4; ++mt) {
#pragma unroll
            for (int e = 0; e < 4; ++e) {
                int m = m0 + wm * 64 + mt * 16 + quad * 4 + e;
                float v = acc[mt][nt][e] + bv;
                if (ACT == 1) v = fmaxf(v, 0.f);
                C[(size_t)m * N + n] = (bf16)v;
            }
        }
    }
}

// ---------------- split-K GEMM: partial-buffer stores (NO atomics), bf16 W ----------------
// Each z-slice writes its partial to Cacc + z*M*N with plain f32 stores;
// reduction is fused into ln_residual_f32. No zero-fill pass needed.
template<int SPLIT>
__global__ __launch_bounds__(512)
void gemm8_splitk(const bf16* __restrict__ A, const bf16* __restrict__ Wfull,
                  float* __restrict__ Cacc, int M, int N, int K)
{
    G8_SWZ_TILE()
    const int Kc = K / SPLIT;
    const bf16* Ab = A + (size_t)blockIdx.z * Kc;
    const bf16* W = Wfull + (size_t)blockIdx.z * Kc;
    float* Cz = Cacc + (size_t)blockIdx.z * M * N;
    G8_PROLOGUE(Ab, W)
    G8_KLOOP(Kc)
#pragma unroll
    for (int nt = 0; nt < 4; ++nt) {
        int n = n0 + wn * 64 + nt * 16 + r;
#pragma unroll
        for (int mt = 0; mt < 4; ++mt) {
#pragma unroll
            for (int e = 0; e < 4; ++e) {
                int m = m0 + wm * 64 + mt * 16 + quad * 4 + e;
                Cz[(size_t)m * N + n] = acc[mt][nt][e];
            }
        }
    }
}

// ---------------- V transpose: qkv v-part [s][h*64+d] -> Vt[h*64+d][s] ----------------
__global__ __launch_bounds__(256)
void transpose_v(const bf16* __restrict__ qkv, bf16* __restrict__ Vt)
{
    __shared__ __bf16 t[64][66];
    const int s0 = blockIdx.x * 64, dm0 = blockIdx.y * 64;
    const int tid = threadIdx.x;
    const int sl = tid >> 2, dc = (tid & 3) * 16;
    const bf16* src = qkv + (size_t)(s0 + sl) * 3072 + 2048 + dm0 + dc;
    bf16x8 v0 = *(const bf16x8*)(src);
    bf16x8 v1 = *(const bf16x8*)(src + 8);
#pragma unroll
    for (int j = 0; j < 8; ++j) { t[sl][dc + j] = v0[j]; t[sl][dc + 8 + j] = v1[j]; }
    __syncthreads();
    const int dl = tid >> 2, sc = (tid & 3) * 16;
    bf16x8 o0, o1;
#pragma unroll
    for (int j = 0; j < 8; ++j) { o0[j] = t[sc + j][dl]; o1[j] = t[sc + 8 + j][dl]; }
    bf16* dst = Vt + (size_t)(dm0 + dl) * SEQ + s0 + sc;
    *(bf16x8*)(dst) = o0;
    *(bf16x8*)(dst + 8) = o1;
}

// ---------------- banded flash attention with MFMA ----------------
__global__ __launch_bounds__(256)
void attn_mfma(const bf16* __restrict__ qkv, const bf16* __restrict__ Vt,
               bf16* __restrict__ o)
{
    __shared__ __align__(16) __bf16 Plds[4][16 * 40];
    const int tid = threadIdx.x, lane = tid & 63, w = tid >> 6;
    const int h = blockIdx.x & 15;
    const int qw = (blockIdx.x >> 4) * 64 + w * 16;
    const int r = lane & 15, quad = lane >> 4;
    __bf16* P = Plds[w];

    bf16x8 qa[2];
    {
        const bf16* qrow = qkv + (size_t)(qw + r) * 3072 + h * 64 + quad * 8;
#pragma unroll
        for (int c = 0; c < 2; ++c) {
            bf16x8 t = *(const bf16x8*)(qrow + c * 32);
#pragma unroll
            for (int j = 0; j < 8; ++j) qa[c][j] = (__bf16)((float)t[j] * 0.125f);
        }
    }

    bf16x8 ones;
#pragma unroll
    for (int j = 0; j < 8; ++j) ones[j] = (__bf16)1.0f;

    f32x4 acc[4];
#pragma unroll
    for (int d = 0; d < 4; ++d) acc[d] = (f32x4){0.f, 0.f, 0.f, 0.f};
    float m_run[4], l_run[4];
#pragma unroll
    for (int e = 0; e < 4; ++e) { m_run[e] = -1e30f; l_run[e] = 0.f; }

    int jmin = qw - (WINDOW - 1); if (jmin < 0) jmin = 0;
    int jmax = qw + 15 + (WINDOW - 1); if (jmax > SEQ - 1) jmax = SEQ - 1;

    for (int kt = jmin & ~31; kt <= jmax; kt += 32) {
        f32x4 S[2];
#pragma unroll
        for (int c = 0; c < 2; ++c) {
            const bf16* krow = qkv + (size_t)(kt + 16 * c + r) * 3072 + 1024 + h * 64 + quad * 8;
            bf16x8 kb0 = *(const bf16x8*)(krow);
            bf16x8 kb1 = *(const bf16x8*)(krow + 32);
            f32x4 s = (f32x4){0.f, 0.f, 0.f, 0.f};
            s = __builtin_amdgcn_mfma_f32_16x16x32_bf16(qa[0], kb0, s, 0, 0, 0);
            s = __builtin_amdgcn_mfma_f32_16x16x32_bf16(qa[1], kb1, s, 0, 0, 0);
            S[c] = s;
        }
#pragma unroll
        for (int c = 0; c < 2; ++c)
#pragma unroll
            for (int e = 0; e < 4; ++e) {
                int j = kt + 16 * c + r;
                int i = qw + quad * 4 + e;
                bool valid = (unsigned)(j - i + (WINDOW - 1)) <= (unsigned)(2 * WINDOW - 2);
                S[c][e] = valid ? S[c][e] : -1e30f;
            }
        float alpha[4], mnew[4];
#pragma unroll
        for (int e = 0; e < 4; ++e) {
            float v = fmaxf(S[0][e], S[1][e]);
#pragma unroll
            for (int off = 1; off <= 8; off <<= 1) v = fmaxf(v, __shfl_xor(v, off, 64));
            mnew[e] = fmaxf(m_run[e], v);
            alpha[e] = __expf(m_run[e] - mnew[e]);
            m_run[e] = mnew[e];
        }
#pragma unroll
        for (int c = 0; c < 2; ++c)
#pragma unroll
            for (int e = 0; e < 4; ++e) {
                float p = __expf(S[c][e] - mnew[e]);
                p = (S[c][e] <= -1e29f) ? 0.f : p;
                P[(quad * 4 + e) * 40 + 16 * c + r] = (__bf16)p;
            }
        bf16x8 pa = *(const bf16x8*)(P + r * 40 + quad * 8);
#pragma unroll
        for (int d = 0; d < 4; ++d)
#pragma unroll
            for (int e = 0; e < 4; ++e) acc[d][e] *= alpha[e];
        f32x4 ls = (f32x4){0.f, 0.f, 0.f, 0.f};
        ls = __builtin_amdgcn_mfma_f32_16x16x32_bf16(pa, ones, ls, 0, 0, 0);
#pragma unroll
        for (int e = 0; e < 4; ++e) l_run[e] = l_run[e] * alpha[e] + ls[e];
#pragma unroll
        for (int d = 0; d < 4; ++d) {
            const bf16* vrow = Vt + (size_t)(h * 64 + 16 * d + r) * SEQ + kt + quad * 8;
            bf16x8 vb = *(const bf16x8*)(vrow);
            acc[d] = __builtin_amdgcn_mfma_f32_16x16x32_bf16(pa, vb, acc[d], 0, 0, 0);
        }
    }

#pragma unroll
    for (int d = 0; d < 4; ++d)
#pragma unroll
        for (int e = 0; e < 4; ++e) {
            int i = qw + quad * 4 + e;
            o[(size_t)i * DMODEL + h * 64 + 16 * d + r] = (bf16)(acc[d][e] / l_run[e]);
        }
}

// ---------------- residual + layernorm, delta = sum of 4 f32 partials + f32 bias ----------------
__global__ __launch_bounds__(256)
void ln_residual_f32(bf16* __restrict__ x, const float* __restrict__ accd,
                     const float* __restrict__ bias,
                     const float* __restrict__ gamma, const float* __restrict__ beta)
{
    const int s = blockIdx.x, tid = threadIdx.x;
    const int lane = tid & 63, wave = tid >> 6;
    __shared__ float red[8];
    float v[4];
    float sum = 0.f;
#pragma unroll
    for (int i = 0; i < 4; ++i) {
        int d = i * 256 + tid;
        float a = accd[(size_t)s * 1024 + d]
                + accd[(size_t)SEQ * 1024 + (size_t)s * 1024 + d]
                + accd[2 * (size_t)SEQ * 1024 + (size_t)s * 1024 + d]
                + accd[3 * (size_t)SEQ * 1024 + (size_t)s * 1024 + d];
        v[i] = (float)x[(size_t)s * 1024 + d] + a + bias[d];
        sum += v[i];
    }
#pragma unroll
    for (int off = 32; off; off >>= 1) sum += __shfl_xor(sum, off, 64);
    if (lane == 0) red[wave] = sum;
    __syncthreads();
    float mu = (red[0] + red[1] + red[2] + red[3]) * (1.f / 1024.f);
    float sq = 0.f;
#pragma unroll
    for (int i = 0; i < 4; ++i) { float t = v[i] - mu; sq += t * t; }
#pragma unroll
    for (int off = 32; off; off >>= 1) sq += __shfl_xor(sq, off, 64);
    if (lane == 0) red[wave + 4] = sq;
    __syncthreads();
    float var = (red[4] + red[5] + red[6] + red[7]) * (1.f / 1024.f);
    float inv = rsqrtf(var + LN_EPS);
#pragma unroll
    for (int i = 0; i < 4; ++i) {
        int d = i * 256 + tid;
        x[(size_t)s * 1024 + d] = (bf16)((v[i] - mu) * inv * gamma[d] + beta[d]);
    }
}

// ---------------- decoder: logits + log_softmax ----------------
__global__ __launch_bounds__(256)
void decoder(const bf16* __restrict__ x, const float* __restrict__ Wdec,
             const float* __restrict__ bdec, float* __restrict__ out)
{
    const int s = blockIdx.x * 4 + (threadIdx.x >> 6);
    const int lane = threadIdx.x & 63;
    float a0 = 0.f, a1 = 0.f, a2 = 0.f;
    for (int d = lane; d < 1024; d += 64) {
        float xv = (float)x[(size_t)s * 1024 + d];
        a0 += xv * Wdec[d];
        a1 += xv * Wdec[1024 + d];
        a2 += xv * Wdec[2048 + d];
    }
#pragma unroll
    for (int off = 32; off; off >>= 1) {
        a0 += __shfl_xor(a0, off, 64);
        a1 += __shfl_xor(a1, off, 64);
        a2 += __shfl_xor(a2, off, 64);
    }
    if (lane == 0) {
        float z0 = a0 + bdec[0];
        float z1 = a1 + bdec[1];
        float z2 = a2 + bdec[2];
        float mx = fmaxf(z0, fmaxf(z1, z2));
        float lse = mx + logf(__expf(z0 - mx) + __expf(z1 - mx) + __expf(z2 - mx));
        out[s * 3 + 0] = z0 - lse;
        out[s * 3 + 1] = z1 - lse;
        out[s * 3 + 2] = z2 - lse;
    }
}

extern "C" void kernel_launch(void* const* d_in, const int* in_sizes, int n_in,
                              void* d_out, int out_size, void* d_ws, size_t ws_size,
                              hipStream_t stream)
{
    const float* X    = (const float*)d_in[0];
    const float* Wqkv = (const float*)d_in[1];
    const float* bqkv = (const float*)d_in[2];
    const float* Wo   = (const float*)d_in[3];
    const float* bo   = (const float*)d_in[4];
    const float* ln1g = (const float*)d_in[5];
    const float* ln1b = (const float*)d_in[6];
    const float* W1   = (const float*)d_in[7];
    const float* b1   = (const float*)d_in[8];
    const float* W2   = (const float*)d_in[9];
    const float* b2   = (const float*)d_in[10];
    const float* ln2g = (const float*)d_in[11];
    const float* ln2b = (const float*)d_in[12];
    const float* Wdec = (const float*)d_in[13];
    const float* bdec = (const float*)d_in[14];

    // workspace (bf16 elems):
    //   x[2M] | buf[8M]=qkv6M/ao2M (reused as h) | Vt[2M]
    //   | accf 4 x 2M f32 split-K partials (32 MB) | Wb[12.583M] per-layer bf16 weights
    bf16* ws   = (bf16*)d_ws;
    bf16* x    = ws;                                  // 2M
    bf16* buf  = x   + (size_t)SEQ * DMODEL;          // 8M
    bf16* qkv  = buf;
    bf16* ao   = buf + (size_t)SEQ * 3 * DMODEL;
    bf16* h    = buf;
    bf16* Vt   = buf + (size_t)SEQ * DFF;             // 2M
    float* accf = (float*)(Vt + (size_t)SEQ * DMODEL);    // 4 x 2M f32 (32 MB)
    bf16* Wb   = (bf16*)(accf + 4 * (size_t)SEQ * DMODEL);
    bf16* WoB  = Wb + 3145728;
    bf16* W1B  = Wb + 4194304;
    bf16* W2B  = Wb + 8388608;

    add_pe<<<(SEQ * DMODEL) / 256, 256, 0, stream>>>(X, x);

    for (int l = 0; l < 4; ++l) {
        // convert this layer's weights f32 -> bf16 (contiguous Wb)
        cvt_w_layer<<<6144, 256, 0, stream>>>(
            Wqkv + (size_t)l * 3145728, Wo + (size_t)l * 1048576,
            W1 + (size_t)l * 4194304,  W2 + (size_t)l * 4194304, Wb);
        // QKV projection
        gemm8_bt<0><<<dim3(3072 / 128, SEQ / 256), 512, 0, stream>>>(
            x, Wb, bqkv + l * 3072, qkv, SEQ, 3072, 1024);
        // banded flash attention
        transpose_v<<<dim3(SEQ / 64, DMODEL / 64), 256, 0, stream>>>(qkv, Vt);
        attn_mfma<<<(SEQ / 64) * NHEAD, 256, 0, stream>>>(qkv, Vt, ao);
        // O projection (split-K=4, partial stores; bias folded into LN)
        gemm8_splitk<4><<<dim3(1024 / 128, SEQ / 256, 4), 512, 0, stream>>>(
            ao, WoB, accf, SEQ, 1024, 1024);
        ln_residual_f32<<<SEQ, 256, 0, stream>>>(x, accf, bo + l * 1024,
                                                 ln1g + l * 1024, ln1b + l * 1024);
        // FF1 (relu, direct) — h overwrites qkv/ao region
        gemm8_bt<1><<<dim3(4096 / 128, SEQ / 256), 512, 0, stream>>>(
            x, W1B, b1 + l * 4096, h, SEQ, 4096, 1024);
        // FF2 (split-K=4, partial stores; bias folded into LN)
        gemm8_splitk<4><<<dim3(1024 / 128, SEQ / 256, 4), 512, 0, stream>>>(
            h, W2B, accf, SEQ, 1024, 4096);
        ln_residual_f32<<<SEQ, 256, 0, stream>>>(x, accf, b2 + l * 1024,
                                                 ln2g + l * 1024, ln2b + l * 1024);
    }

    decoder<<<SEQ / 4, 256, 0, stream>>>(x, Wdec, bdec, (float*)d_out);
}

// Round 7
// 811.232 us; speedup vs baseline: 1.2140x; 1.0170x over previous
//
#include <hip/hip_runtime.h>
#include <hip/hip_bf16.h>
#include <cmath>

typedef __hip_bfloat16 bf16;
typedef __bf16 bf16x8 __attribute__((ext_vector_type(8)));
typedef __bf16 bf16x4 __attribute__((ext_vector_type(4)));
typedef float f32x4 __attribute__((ext_vector_type(4)));

typedef __attribute__((address_space(1))) void void_g;
typedef __attribute__((address_space(3))) void void_l;

#define SEQ 2048
#define DMODEL 1024
#define NHEAD 16
#define HDIM 64
#define DFF 4096
#define WINDOW 128
#define LN_EPS 1e-5f

__device__ __forceinline__ void gl_lds16(const bf16* g, bf16* l) {
    __builtin_amdgcn_global_load_lds((void_g*)(g), (void_l*)(l), 16, 0, 0);
}

__device__ __forceinline__ bf16x8 cvt8(float4 a, float4 b) {
    bf16x8 w;
    w[0] = (__bf16)a.x; w[1] = (__bf16)a.y; w[2] = (__bf16)a.z; w[3] = (__bf16)a.w;
    w[4] = (__bf16)b.x; w[5] = (__bf16)b.y; w[6] = (__bf16)b.z; w[7] = (__bf16)b.w;
    return w;
}

// ---------------- positional encoding add: f32 in -> bf16 out ----------------
__global__ __launch_bounds__(256)
void add_pe(const float* __restrict__ X, bf16* __restrict__ x) {
    int idx = blockIdx.x * 256 + threadIdx.x;
    int s = idx >> 10, d = idx & 1023;
    float i2 = (float)(d & ~1);
    float div = expf(i2 * (-9.210340371976184f / 1024.0f));
    float ang = (float)s * div;
    float pe = (d & 1) ? cosf(ang) : sinf(ang);
    x[idx] = (bf16)(X[idx] + pe);
}

// ---------------- per-layer weight f32 -> bf16 conversion ----------------
// dst layout (bf16 elems): qkv[3072x1024] | wo[1024x1024] | w1[4096x1024] | w2[1024x4096]
__global__ __launch_bounds__(256)
void cvt_w_layer(const float* __restrict__ wqkv, const float* __restrict__ wo,
                 const float* __restrict__ w1, const float* __restrict__ w2,
                 bf16* __restrict__ dst)
{
    int i = blockIdx.x * 256 + threadIdx.x;   // 8-elem group id, [0, 1572864)
    const float* src; size_t so;
    if (i < 393216)       { src = wqkv; so = (size_t)i * 8; }
    else if (i < 524288)  { src = wo;   so = (size_t)(i - 393216) * 8; }
    else if (i < 1048576) { src = w1;   so = (size_t)(i - 524288) * 8; }
    else                  { src = w2;   so = (size_t)(i - 1048576) * 8; }
    float4 a = *(const float4*)(src + so);
    float4 b = *(const float4*)(src + so + 4);
    *(bf16x8*)(dst + (size_t)i * 8) = cvt8(a, b);
}

// ======================= minimal-2-phase GEMM core: 256M x 128N, BK=64 =======================
// 512 threads = 8 waves (4M x 2N), each wave computes 64x64 (acc[4][4]).
// Per K-step: {issue 6 gl_lds for t+2 | 16 ds_read_b128 for step t |
//              32 MFMA (setprio-wrapped) | s_waitcnt vmcnt(6) | raw s_barrier}
// ONE barrier per K-step; vmcnt NEVER 0 mid-loop. Triple-buffered LDS (144 KiB).
// LDS layout per buffer, per ks-half (32 k-elems): [rows][32], chunk-XOR
// swizzle kch=(c&3)^(row&3); source address pre-swizzled so LDS stays linear.
// Frag read: half ks: base + ks*ROWS*32 + row*32 + (quad^(r&3))*8.
//
// Block->tile mapping: L2-CAPACITY-AWARE XCD swizzle. HW maps linear block id
// l to XCD l%8 (round-robin). We remap so XCD k computes a RECTANGLE of tiles
// whose combined A-slice + W-slice working set fits the XCD's private 4 MiB L2
// (the R6 m-panel swizzle required ALL of W per XCD -> 8x W re-fetch from HBM;
// FETCH_SIZE showed 2.9x over-fetch and every GEMM ran at hbm_bytes/2TB/s).

#define G8_PROLOGUE(Adecl, Wdecl)                                                \
    __shared__ __align__(16) bf16 AS[3][256 * 64];                               \
    __shared__ __align__(16) bf16 BS[3][128 * 64];                               \
    const int tid  = threadIdx.x;                                                \
    const int lane = tid & 63;                                                   \
    const int wave = tid >> 6;                                                   \
    const int wm = wave >> 1, wn = wave & 1;                                     \
    const int r = lane & 15, quad = lane >> 4;                                   \
    const int rc = (quad ^ (r & 3)) * 8;                                         \
    f32x4 acc[4][4];                                                             \
    _Pragma("unroll")                                                            \
    for (int i = 0; i < 4; ++i)                                                  \
        _Pragma("unroll")                                                        \
        for (int j = 0; j < 4; ++j) acc[i][j] = (f32x4){0.f, 0.f, 0.f, 0.f};     \
    const bf16* ApA[4]; const bf16* ApB[2];                                      \
    _Pragma("unroll")                                                            \
    for (int i = 0; i < 4; ++i) {                                                \
        int c = tid + 512 * i;                                                   \
        int ks = c >> 10, row = (c >> 2) & 255, kch = (c & 3) ^ (row & 3);       \
        ApA[i] = (Adecl) + (size_t)(m0 + row) * K + ks * 32 + kch * 8;           \
    }                                                                            \
    _Pragma("unroll")                                                            \
    for (int i = 0; i < 2; ++i) {                                                \
        int c = tid + 512 * i;                                                   \
        int ks = c >> 9, row = (c >> 2) & 127, kch = (c & 3) ^ (row & 3);        \
        ApB[i] = (Wdecl) + (size_t)(n0 + row) * K + ks * 32 + kch * 8;           \
    }

#define G8_STAGE(koff, Adst, Bdst)                                               \
    _Pragma("unroll")                                                            \
    for (int i = 0; i < 4; ++i)                                                  \
        gl_lds16(ApA[i] + (koff), (Adst) + (size_t)(tid + 512 * i) * 8);         \
    _Pragma("unroll")                                                            \
    for (int i = 0; i < 2; ++i)                                                  \
        gl_lds16(ApB[i] + (koff), (Bdst) + (size_t)(tid + 512 * i) * 8);

#define G8_KLOOP(Klim)                                                           \
    const int nit = (Klim) / 64;                                                 \
    bf16 *A_c = &AS[0][0], *A_n = &AS[1][0], *A_f = &AS[2][0];                   \
    bf16 *B_c = &BS[0][0], *B_n = &BS[1][0], *B_f = &BS[2][0];                   \
    G8_STAGE(0, A_c, B_c)                                                        \
    if (nit > 1) {                                                               \
        G8_STAGE(64, A_n, B_n)                                                   \
        asm volatile("s_waitcnt vmcnt(6)" ::: "memory");                         \
    } else {                                                                     \
        asm volatile("s_waitcnt vmcnt(0)" ::: "memory");                         \
    }                                                                            \
    __builtin_amdgcn_s_barrier();                                                \
    for (int t = 0; t < nit; ++t) {                                              \
        const bool stg = (t + 2 < nit);                                          \
        if (stg) { G8_STAGE((t + 2) * 64, A_f, B_f) }                            \
        bf16x8 av[4][2], bv[4][2];                                               \
        _Pragma("unroll")                                                        \
        for (int mf = 0; mf < 4; ++mf)                                           \
            _Pragma("unroll")                                                    \
            for (int kk = 0; kk < 2; ++kk)                                       \
                av[mf][kk] = *(const bf16x8*)(A_c + kk * 8192 +                  \
                              (wm * 64 + mf * 16 + r) * 32 + rc);                \
        _Pragma("unroll")                                                        \
        for (int nf = 0; nf < 4; ++nf)                                           \
            _Pragma("unroll")                                                    \
            for (int kk = 0; kk < 2; ++kk)                                       \
                bv[nf][kk] = *(const bf16x8*)(B_c + kk * 4096 +                  \
                              (wn * 64 + nf * 16 + r) * 32 + rc);                \
        __builtin_amdgcn_s_setprio(1);                                           \
        _Pragma("unroll")                                                        \
        for (int mf = 0; mf < 4; ++mf)                                           \
            _Pragma("unroll")                                                    \
            for (int nf = 0; nf < 4; ++nf)                                       \
                _Pragma("unroll")                                                \
                for (int kk = 0; kk < 2; ++kk)                                   \
                    acc[mf][nf] = __builtin_amdgcn_mfma_f32_16x16x32_bf16(       \
                        av[mf][kk], bv[nf][kk], acc[mf][nf], 0, 0, 0);           \
        __builtin_amdgcn_s_setprio(0);                                           \
        if (stg) asm volatile("s_waitcnt vmcnt(6)" ::: "memory");                \
        else     asm volatile("s_waitcnt vmcnt(0)" ::: "memory");                \
        __builtin_amdgcn_s_barrier();                                            \
        bf16* tA = A_c; A_c = A_n; A_n = A_f; A_f = tA;                          \
        bf16* tB = B_c; B_c = B_n; B_n = B_f; B_f = tB;                          \
    }

// ---------------- direct GEMM: C[M,N] = A[M,K]*W[N,K]^T + bias, bf16 W ----------------
// XCD rect: SX x-tiles x SY y-tiles per XCD ((gx/SX)*(gy/SY) must == 8).
// VOUT: n-tiles at n0 >= 2048 (the V third of QKV) are written TRANSPOSED to
// Vt[d][s] instead of C (kills the separate transpose_v pass).
template<int ACT, int SX, int SY, int VOUT>
__global__ __launch_bounds__(512)
void gemm8_bt(const bf16* __restrict__ A, const bf16* __restrict__ W,
              const float* __restrict__ bias, bf16* __restrict__ C,
              bf16* __restrict__ Vt, int M, int N, int K)
{
    const int gx = gridDim.x;
    const int l = blockIdx.y * gx + blockIdx.x;
    const int k = l & 7, j = l >> 3;
    const int xg = gx / SX;
    const int tx = (k % xg) * SX + (j % SX);
    const int ty = (k / xg) * SY + (j / SX);
    const int m0 = ty * 256, n0 = tx * 128;
    G8_PROLOGUE(A, W)
    G8_KLOOP(K)
    if (VOUT && n0 >= 2048) {
#pragma unroll
        for (int nt = 0; nt < 4; ++nt) {
            int n = n0 + wn * 64 + nt * 16 + r;
            float bv = bias[n];
            int dv = n - 2048;
#pragma unroll
            for (int mt = 0; mt < 4; ++mt) {
                int m = m0 + wm * 64 + mt * 16 + quad * 4;
                bf16x4 pk;
#pragma unroll
                for (int e = 0; e < 4; ++e) pk[e] = (__bf16)(acc[mt][nt][e] + bv);
                *(bf16x4*)(Vt + (size_t)dv * SEQ + m) = pk;
            }
        }
    } else {
#pragma unroll
        for (int nt = 0; nt < 4; ++nt) {
            int n = n0 + wn * 64 + nt * 16 + r;
            float bv = bias[n];
#pragma unroll
            for (int mt = 0; mt < 4; ++mt) {
#pragma unroll
                for (int e = 0; e < 4; ++e) {
                    int m = m0 + wm * 64 + mt * 16 + quad * 4 + e;
                    float v = acc[mt][nt][e] + bv;
                    if (ACT == 1) v = fmaxf(v, 0.f);
                    C[(size_t)m * N + n] = (bf16)v;
                }
            }
        }
    }
}

// ---------------- split-K GEMM: partial-buffer stores (NO atomics), bf16 W ----------------
// XCD rect: all gx x-tiles x SY y-tiles x 1 z-slice per XCD ((gy/SY)*gz == 8).
// Each z-slice writes its partial to Cacc + z*M*N; reduction fused into LN.
template<int SPLIT, int SY>
__global__ __launch_bounds__(512)
void gemm8_splitk(const bf16* __restrict__ A, const bf16* __restrict__ Wfull,
                  float* __restrict__ Cacc, int M, int N, int K)
{
    const int gx = gridDim.x, gy = gridDim.y;
    const int l = (blockIdx.z * gy + blockIdx.y) * gx + blockIdx.x;
    const int k = l & 7, j = l >> 3;
    const int yg = gy / SY;
    const int tx = j % gx;
    const int ty = (k % yg) * SY + (j / gx);
    const int tz = k / yg;
    const int m0 = ty * 256, n0 = tx * 128;
    const int Kc = K / SPLIT;
    const bf16* Ab = A + (size_t)tz * Kc;
    const bf16* W = Wfull + (size_t)tz * Kc;
    float* Cz = Cacc + (size_t)tz * M * N;
    G8_PROLOGUE(Ab, W)
    G8_KLOOP(Kc)
#pragma unroll
    for (int nt = 0; nt < 4; ++nt) {
        int n = n0 + wn * 64 + nt * 16 + r;
#pragma unroll
        for (int mt = 0; mt < 4; ++mt) {
#pragma unroll
            for (int e = 0; e < 4; ++e) {
                int m = m0 + wm * 64 + mt * 16 + quad * 4 + e;
                Cz[(size_t)m * N + n] = acc[mt][nt][e];
            }
        }
    }
}

// ---------------- banded flash attention with MFMA ----------------
__global__ __launch_bounds__(256)
void attn_mfma(const bf16* __restrict__ qkv, const bf16* __restrict__ Vt,
               bf16* __restrict__ o)
{
    __shared__ __align__(16) __bf16 Plds[4][16 * 40];
    const int tid = threadIdx.x, lane = tid & 63, w = tid >> 6;
    const int h = blockIdx.x & 15;
    const int qw = (blockIdx.x >> 4) * 64 + w * 16;
    const int r = lane & 15, quad = lane >> 4;
    __bf16* P = Plds[w];

    bf16x8 qa[2];
    {
        const bf16* qrow = qkv + (size_t)(qw + r) * 3072 + h * 64 + quad * 8;
#pragma unroll
        for (int c = 0; c < 2; ++c) {
            bf16x8 t = *(const bf16x8*)(qrow + c * 32);
#pragma unroll
            for (int j = 0; j < 8; ++j) qa[c][j] = (__bf16)((float)t[j] * 0.125f);
        }
    }

    bf16x8 ones;
#pragma unroll
    for (int j = 0; j < 8; ++j) ones[j] = (__bf16)1.0f;

    f32x4 acc[4];
#pragma unroll
    for (int d = 0; d < 4; ++d) acc[d] = (f32x4){0.f, 0.f, 0.f, 0.f};
    float m_run[4], l_run[4];
#pragma unroll
    for (int e = 0; e < 4; ++e) { m_run[e] = -1e30f; l_run[e] = 0.f; }

    int jmin = qw - (WINDOW - 1); if (jmin < 0) jmin = 0;
    int jmax = qw + 15 + (WINDOW - 1); if (jmax > SEQ - 1) jmax = SEQ - 1;

    for (int kt = jmin & ~31; kt <= jmax; kt += 32) {
        f32x4 S[2];
#pragma unroll
        for (int c = 0; c < 2; ++c) {
            const bf16* krow = qkv + (size_t)(kt + 16 * c + r) * 3072 + 1024 + h * 64 + quad * 8;
            bf16x8 kb0 = *(const bf16x8*)(krow);
            bf16x8 kb1 = *(const bf16x8*)(krow + 32);
            f32x4 s = (f32x4){0.f, 0.f, 0.f, 0.f};
            s = __builtin_amdgcn_mfma_f32_16x16x32_bf16(qa[0], kb0, s, 0, 0, 0);
            s = __builtin_amdgcn_mfma_f32_16x16x32_bf16(qa[1], kb1, s, 0, 0, 0);
            S[c] = s;
        }
#pragma unroll
        for (int c = 0; c < 2; ++c)
#pragma unroll
            for (int e = 0; e < 4; ++e) {
                int j = kt + 16 * c + r;
                int i = qw + quad * 4 + e;
                bool valid = (unsigned)(j - i + (WINDOW - 1)) <= (unsigned)(2 * WINDOW - 2);
                S[c][e] = valid ? S[c][e] : -1e30f;
            }
        float alpha[4], mnew[4];
#pragma unroll
        for (int e = 0; e < 4; ++e) {
            float v = fmaxf(S[0][e], S[1][e]);
#pragma unroll
            for (int off = 1; off <= 8; off <<= 1) v = fmaxf(v, __shfl_xor(v, off, 64));
            mnew[e] = fmaxf(m_run[e], v);
            alpha[e] = __expf(m_run[e] - mnew[e]);
            m_run[e] = mnew[e];
        }
#pragma unroll
        for (int c = 0; c < 2; ++c)
#pragma unroll
            for (int e = 0; e < 4; ++e) {
                float p = __expf(S[c][e] - mnew[e]);
                p = (S[c][e] <= -1e29f) ? 0.f : p;
                P[(quad * 4 + e) * 40 + 16 * c + r] = (__bf16)p;
            }
        bf16x8 pa = *(const bf16x8*)(P + r * 40 + quad * 8);
#pragma unroll
        for (int d = 0; d < 4; ++d)
#pragma unroll
            for (int e = 0; e < 4; ++e) acc[d][e] *= alpha[e];
        f32x4 ls = (f32x4){0.f, 0.f, 0.f, 0.f};
        ls = __builtin_amdgcn_mfma_f32_16x16x32_bf16(pa, ones, ls, 0, 0, 0);
#pragma unroll
        for (int e = 0; e < 4; ++e) l_run[e] = l_run[e] * alpha[e] + ls[e];
#pragma unroll
        for (int d = 0; d < 4; ++d) {
            const bf16* vrow = Vt + (size_t)(h * 64 + 16 * d + r) * SEQ + kt + quad * 8;
            bf16x8 vb = *(const bf16x8*)(vrow);
            acc[d] = __builtin_amdgcn_mfma_f32_16x16x32_bf16(pa, vb, acc[d], 0, 0, 0);
        }
    }

#pragma unroll
    for (int d = 0; d < 4; ++d)
#pragma unroll
        for (int e = 0; e < 4; ++e) {
            int i = qw + quad * 4 + e;
            o[(size_t)i * DMODEL + h * 64 + 16 * d + r] = (bf16)(acc[d][e] / l_run[e]);
        }
}

// ---------------- residual + layernorm, delta = sum of 4 f32 partials + f32 bias ----------------
__global__ __launch_bounds__(256)
void ln_residual_f32(bf16* __restrict__ x, const float* __restrict__ accd,
                     const float* __restrict__ bias,
                     const float* __restrict__ gamma, const float* __restrict__ beta)
{
    const int s = blockIdx.x, tid = threadIdx.x;
    const int lane = tid & 63, wave = tid >> 6;
    __shared__ float red[8];
    float v[4];
    float sum = 0.f;
#pragma unroll
    for (int i = 0; i < 4; ++i) {
        int d = i * 256 + tid;
        float a = accd[(size_t)s * 1024 + d]
                + accd[(size_t)SEQ * 1024 + (size_t)s * 1024 + d]
                + accd[2 * (size_t)SEQ * 1024 + (size_t)s * 1024 + d]
                + accd[3 * (size_t)SEQ * 1024 + (size_t)s * 1024 + d];
        v[i] = (float)x[(size_t)s * 1024 + d] + a + bias[d];
        sum += v[i];
    }
#pragma unroll
    for (int off = 32; off; off >>= 1) sum += __shfl_xor(sum, off, 64);
    if (lane == 0) red[wave] = sum;
    __syncthreads();
    float mu = (red[0] + red[1] + red[2] + red[3]) * (1.f / 1024.f);
    float sq = 0.f;
#pragma unroll
    for (int i = 0; i < 4; ++i) { float t = v[i] - mu; sq += t * t; }
#pragma unroll
    for (int off = 32; off; off >>= 1) sq += __shfl_xor(sq, off, 64);
    if (lane == 0) red[wave + 4] = sq;
    __syncthreads();
    float var = (red[4] + red[5] + red[6] + red[7]) * (1.f / 1024.f);
    float inv = rsqrtf(var + LN_EPS);
#pragma unroll
    for (int i = 0; i < 4; ++i) {
        int d = i * 256 + tid;
        x[(size_t)s * 1024 + d] = (bf16)((v[i] - mu) * inv * gamma[d] + beta[d]);
    }
}

// ---------------- decoder: logits + log_softmax ----------------
__global__ __launch_bounds__(256)
void decoder(const bf16* __restrict__ x, const float* __restrict__ Wdec,
             const float* __restrict__ bdec, float* __restrict__ out)
{
    const int s = blockIdx.x * 4 + (threadIdx.x >> 6);
    const int lane = threadIdx.x & 63;
    float a0 = 0.f, a1 = 0.f, a2 = 0.f;
    for (int d = lane; d < 1024; d += 64) {
        float xv = (float)x[(size_t)s * 1024 + d];
        a0 += xv * Wdec[d];
        a1 += xv * Wdec[1024 + d];
        a2 += xv * Wdec[2048 + d];
    }
#pragma unroll
    for (int off = 32; off; off >>= 1) {
        a0 += __shfl_xor(a0, off, 64);
        a1 += __shfl_xor(a1, off, 64);
        a2 += __shfl_xor(a2, off, 64);
    }
    if (lane == 0) {
        float z0 = a0 + bdec[0];
        float z1 = a1 + bdec[1];
        float z2 = a2 + bdec[2];
        float mx = fmaxf(z0, fmaxf(z1, z2));
        float lse = mx + logf(__expf(z0 - mx) + __expf(z1 - mx) + __expf(z2 - mx));
        out[s * 3 + 0] = z0 - lse;
        out[s * 3 + 1] = z1 - lse;
        out[s * 3 + 2] = z2 - lse;
    }
}

extern "C" void kernel_launch(void* const* d_in, const int* in_sizes, int n_in,
                              void* d_out, int out_size, void* d_ws, size_t ws_size,
                              hipStream_t stream)
{
    const float* X    = (const float*)d_in[0];
    const float* Wqkv = (const float*)d_in[1];
    const float* bqkv = (const float*)d_in[2];
    const float* Wo   = (const float*)d_in[3];
    const float* bo   = (const float*)d_in[4];
    const float* ln1g = (const float*)d_in[5];
    const float* ln1b = (const float*)d_in[6];
    const float* W1   = (const float*)d_in[7];
    const float* b1   = (const float*)d_in[8];
    const float* W2   = (const float*)d_in[9];
    const float* b2   = (const float*)d_in[10];
    const float* ln2g = (const float*)d_in[11];
    const float* ln2b = (const float*)d_in[12];
    const float* Wdec = (const float*)d_in[13];
    const float* bdec = (const float*)d_in[14];

    // workspace (bf16 elems):
    //   x[2M] | buf[8M]=qkv6M/ao2M (reused as h) | Vt[2M]
    //   | accf 4 x 2M f32 split-K partials (32 MB) | Wb[12.583M] per-layer bf16 weights
    bf16* ws   = (bf16*)d_ws;
    bf16* x    = ws;                                  // 2M
    bf16* buf  = x   + (size_t)SEQ * DMODEL;          // 8M
    bf16* qkv  = buf;
    bf16* ao   = buf + (size_t)SEQ * 3 * DMODEL;
    bf16* h    = buf;
    bf16* Vt   = buf + (size_t)SEQ * DFF;             // 2M
    float* accf = (float*)(Vt + (size_t)SEQ * DMODEL);    // 4 x 2M f32 (32 MB)
    bf16* Wb   = (bf16*)(accf + 4 * (size_t)SEQ * DMODEL);
    bf16* WoB  = Wb + 3145728;
    bf16* W1B  = Wb + 4194304;
    bf16* W2B  = Wb + 8388608;

    add_pe<<<(SEQ * DMODEL) / 256, 256, 0, stream>>>(X, x);

    for (int l = 0; l < 4; ++l) {
        // convert this layer's weights f32 -> bf16 (contiguous Wb)
        cvt_w_layer<<<6144, 256, 0, stream>>>(
            Wqkv + (size_t)l * 3145728, Wo + (size_t)l * 1048576,
            W1 + (size_t)l * 4194304,  W2 + (size_t)l * 4194304, Wb);
        // QKV projection; V third written transposed straight into Vt.
        // XCD rect 6x x 4y: W-slice 1.5MB + A-slice 2MB fits 4MB L2.
        gemm8_bt<0, 6, 4, 1><<<dim3(3072 / 128, SEQ / 256), 512, 0, stream>>>(
            x, Wb, bqkv + l * 3072, qkv, Vt, SEQ, 3072, 1024);
        // banded flash attention
        attn_mfma<<<(SEQ / 64) * NHEAD, 256, 0, stream>>>(qkv, Vt, ao);
        // O projection (split-K=4, partial stores; bias folded into LN)
        // XCD rect: all-x x 4y x 1z: W z-slice 0.5MB + A 0.5MB.
        gemm8_splitk<4, 4><<<dim3(1024 / 128, SEQ / 256, 4), 512, 0, stream>>>(
            ao, WoB, accf, SEQ, 1024, 1024);
        ln_residual_f32<<<SEQ, 256, 0, stream>>>(x, accf, bo + l * 1024,
                                                 ln1g + l * 1024, ln1b + l * 1024);
        // FF1 (relu, direct) — h overwrites qkv/ao region
        // XCD rect 8x x 4y: W-slice 2MB + A-slice 2MB.
        gemm8_bt<1, 8, 4, 0><<<dim3(4096 / 128, SEQ / 256), 512, 0, stream>>>(
            x, W1B, b1 + l * 4096, h, nullptr, SEQ, 4096, 1024);
        // FF2 (split-K=4, partial stores; bias folded into LN)
        // XCD rect: all-x x 4y x 1z: W z-slice 2MB + A-slice 2MB.
        gemm8_splitk<4, 4><<<dim3(1024 / 128, SEQ / 256, 4), 512, 0, stream>>>(
            h, W2B, accf, SEQ, 1024, 4096);
        ln_residual_f32<<<SEQ, 256, 0, stream>>>(x, accf, b2 + l * 1024,
                                                 ln2g + l * 1024, ln2b + l * 1024);
    }

    decoder<<<SEQ / 4, 256, 0, stream>>>(x, Wdec, bdec, (float*)d_out);
}

// Round 9
// 730.894 us; speedup vs baseline: 1.3475x; 1.1099x over previous
//
#include <hip/hip_runtime.h>
#include <hip/hip_bf16.h>
#include <cmath>

typedef __hip_bfloat16 bf16;
typedef __bf16 bf16x8 __attribute__((ext_vector_type(8)));
typedef __bf16 bf16x4 __attribute__((ext_vector_type(4)));
typedef float f32x4 __attribute__((ext_vector_type(4)));

typedef __attribute__((address_space(1))) void void_g;
typedef __attribute__((address_space(3))) void void_l;

#define SEQ 2048
#define DMODEL 1024
#define NHEAD 16
#define HDIM 64
#define DFF 4096
#define WINDOW 128
#define LN_EPS 1e-5f

__device__ __forceinline__ void gl_lds16(const bf16* g, bf16* l) {
    __builtin_amdgcn_global_load_lds((void_g*)(g), (void_l*)(l), 16, 0, 0);
}

__device__ __forceinline__ bf16x8 cvt8(float4 a, float4 b) {
    bf16x8 w;
    w[0] = (__bf16)a.x; w[1] = (__bf16)a.y; w[2] = (__bf16)a.z; w[3] = (__bf16)a.w;
    w[4] = (__bf16)b.x; w[5] = (__bf16)b.y; w[6] = (__bf16)b.z; w[7] = (__bf16)b.w;
    return w;
}

// ---------------- positional encoding add: f32 in -> bf16 out ----------------
__global__ __launch_bounds__(256)
void add_pe(const float* __restrict__ X, bf16* __restrict__ x) {
    int idx = blockIdx.x * 256 + threadIdx.x;
    int s = idx >> 10, d = idx & 1023;
    float i2 = (float)(d & ~1);
    float div = expf(i2 * (-9.210340371976184f / 1024.0f));
    float ang = (float)s * div;
    float pe = (d & 1) ? cosf(ang) : sinf(ang);
    x[idx] = (bf16)(X[idx] + pe);
}

// ---------------- per-layer weight f32 -> bf16 conversion ----------------
// dst layout (bf16 elems): qkv[3072x1024] | wo[1024x1024] | w1[4096x1024] | w2[1024x4096]
__global__ __launch_bounds__(256)
void cvt_w_layer(const float* __restrict__ wqkv, const float* __restrict__ wo,
                 const float* __restrict__ w1, const float* __restrict__ w2,
                 bf16* __restrict__ dst)
{
    int i = blockIdx.x * 256 + threadIdx.x;   // 8-elem group id, [0, 1572864)
    const float* src; size_t so;
    if (i < 393216)       { src = wqkv; so = (size_t)i * 8; }
    else if (i < 524288)  { src = wo;   so = (size_t)(i - 393216) * 8; }
    else if (i < 1048576) { src = w1;   so = (size_t)(i - 524288) * 8; }
    else                  { src = w2;   so = (size_t)(i - 1048576) * 8; }
    float4 a = *(const float4*)(src + so);
    float4 b = *(const float4*)(src + so + 4);
    *(bf16x8*)(dst + (size_t)i * 8) = cvt8(a, b);
}

// ======================= GEMM core: 128M x 128N, BK=64, 2 blocks/CU =======================
// 256 threads = 4 waves (2M x 2N), each wave computes 64x64 (acc[4][4]) -- the
// proven m97 per-wave shape. Double-buffered LDS (64 KiB total) so TWO blocks
// co-reside per CU: when one block sits in its end-of-step vmcnt(0) wait, the
// other issues MFMA (m114 mechanism -- TLP, not intra-block pipelining, is what
// hides the drain; our previous 256-row tiles were 144 KiB = 1 block/CU and
// every schedule variant was equally starved).
// Per K-step: {stage t+1 into buf^1 (8 gl_lds) | 16 ds_read_b128 | 32 MFMA
//              (setprio) | s_waitcnt vmcnt(0) | raw s_barrier | swap}.
// LDS layout per buffer, per ks-half (32 k): [128 rows][32], chunk-XOR swizzle
// kch=(c&3)^(row&3); source address pre-swizzled so LDS stays linear.
// Frag read: half ks: base + ks*4096 + row*32 + (quad^(r&3))*8.

#define G_PROLOGUE(Adecl, Wdecl)                                                 \
    __shared__ __align__(16) bf16 AS[2][128 * 64];                               \
    __shared__ __align__(16) bf16 BS[2][128 * 64];                               \
    const int tid  = threadIdx.x;                                                \
    const int lane = tid & 63;                                                   \
    const int wave = tid >> 6;                                                   \
    const int wm = wave >> 1, wn = wave & 1;                                     \
    const int r = lane & 15, quad = lane >> 4;                                   \
    const int rc = (quad ^ (r & 3)) * 8;                                         \
    f32x4 acc[4][4];                                                             \
    _Pragma("unroll")                                                            \
    for (int i = 0; i < 4; ++i)                                                  \
        _Pragma("unroll")                                                        \
        for (int j = 0; j < 4; ++j) acc[i][j] = (f32x4){0.f, 0.f, 0.f, 0.f};     \
    const bf16* Ap[4]; const bf16* Bp[4];                                        \
    _Pragma("unroll")                                                            \
    for (int i = 0; i < 4; ++i) {                                                \
        int c = tid + 256 * i;                                                   \
        int ks = c >> 9, row = (c >> 2) & 127, kch = (c & 3) ^ (row & 3);        \
        Ap[i] = (Adecl) + (size_t)(m0 + row) * K + ks * 32 + kch * 8;            \
        Bp[i] = (Wdecl) + (size_t)(n0 + row) * K + ks * 32 + kch * 8;            \
    }

#define G_STAGE(koff, Ad, Bd)                                                    \
    _Pragma("unroll")                                                            \
    for (int i = 0; i < 4; ++i)                                                  \
        gl_lds16(Ap[i] + (koff), (Ad) + (size_t)(tid + 256 * i) * 8);            \
    _Pragma("unroll")                                                            \
    for (int i = 0; i < 4; ++i)                                                  \
        gl_lds16(Bp[i] + (koff), (Bd) + (size_t)(tid + 256 * i) * 8);

#define G_KLOOP(Klim)                                                            \
    const int nit = (Klim) / 64;                                                 \
    bf16 *A_c = &AS[0][0], *A_n = &AS[1][0];                                     \
    bf16 *B_c = &BS[0][0], *B_n = &BS[1][0];                                     \
    G_STAGE(0, A_c, B_c)                                                         \
    asm volatile("s_waitcnt vmcnt(0)" ::: "memory");                             \
    __builtin_amdgcn_s_barrier();                                                \
    for (int t = 0; t < nit; ++t) {                                              \
        if (t + 1 < nit) { G_STAGE((t + 1) * 64, A_n, B_n) }                     \
        bf16x8 av[4][2], bv[4][2];                                               \
        _Pragma("unroll")                                                        \
        for (int mf = 0; mf < 4; ++mf)                                           \
            _Pragma("unroll")                                                    \
            for (int kk = 0; kk < 2; ++kk)                                       \
                av[mf][kk] = *(const bf16x8*)(A_c + kk * 4096 +                  \
                              (wm * 64 + mf * 16 + r) * 32 + rc);                \
        _Pragma("unroll")                                                        \
        for (int nf = 0; nf < 4; ++nf)                                           \
            _Pragma("unroll")                                                    \
            for (int kk = 0; kk < 2; ++kk)                                       \
                bv[nf][kk] = *(const bf16x8*)(B_c + kk * 4096 +                  \
                              (wn * 64 + nf * 16 + r) * 32 + rc);                \
        __builtin_amdgcn_s_setprio(1);                                           \
        _Pragma("unroll")                                                        \
        for (int mf = 0; mf < 4; ++mf)                                           \
            _Pragma("unroll")                                                    \
            for (int nf = 0; nf < 4; ++nf)                                       \
                _Pragma("unroll")                                                \
                for (int kk = 0; kk < 2; ++kk)                                   \
                    acc[mf][nf] = __builtin_amdgcn_mfma_f32_16x16x32_bf16(       \
                        av[mf][kk], bv[nf][kk], acc[mf][nf], 0, 0, 0);           \
        __builtin_amdgcn_s_setprio(0);                                           \
        asm volatile("s_waitcnt vmcnt(0)" ::: "memory");                         \
        __builtin_amdgcn_s_barrier();                                            \
        bf16* tA = A_c; A_c = A_n; A_n = tA;                                     \
        bf16* tB = B_c; B_c = B_n; B_n = tB;                                     \
    }

// ---------------- direct GEMM: C[M,N] = A[M,K]*W[N,K]^T + bias, bf16 W ----------------
// XCD rect: SX x-tiles x SY y-tiles per XCD ((gx/SX)*(gy/SY) must == 8).
// VOUT: n-tiles at n0 >= 2048 (the V third of QKV) are written TRANSPOSED to
// Vt[d][s] instead of C.
template<int ACT, int SX, int SY, int VOUT>
__global__ __launch_bounds__(256)
void gemm8_bt(const bf16* __restrict__ A, const bf16* __restrict__ W,
              const float* __restrict__ bias, bf16* __restrict__ C,
              bf16* __restrict__ Vt, int M, int N, int K)
{
    const int gx = gridDim.x;
    const int l = blockIdx.y * gx + blockIdx.x;
    const int k = l & 7, j = l >> 3;
    const int xg = gx / SX;
    const int tx = (k % xg) * SX + (j % SX);
    const int ty = (k / xg) * SY + (j / SX);
    const int m0 = ty * 128, n0 = tx * 128;
    G_PROLOGUE(A, W)
    G_KLOOP(K)
    if (VOUT && n0 >= 2048) {
#pragma unroll
        for (int nt = 0; nt < 4; ++nt) {
            int n = n0 + wn * 64 + nt * 16 + r;
            float bv = bias[n];
            int dv = n - 2048;
#pragma unroll
            for (int mt = 0; mt < 4; ++mt) {
                int m = m0 + wm * 64 + mt * 16 + quad * 4;
                bf16x4 pk;
#pragma unroll
                for (int e = 0; e < 4; ++e) pk[e] = (__bf16)(acc[mt][nt][e] + bv);
                *(bf16x4*)(Vt + (size_t)dv * SEQ + m) = pk;
            }
        }
    } else {
#pragma unroll
        for (int nt = 0; nt < 4; ++nt) {
            int n = n0 + wn * 64 + nt * 16 + r;
            float bv = bias[n];
#pragma unroll
            for (int mt = 0; mt < 4; ++mt) {
#pragma unroll
                for (int e = 0; e < 4; ++e) {
                    int m = m0 + wm * 64 + mt * 16 + quad * 4 + e;
                    float v = acc[mt][nt][e] + bv;
                    if (ACT == 1) v = fmaxf(v, 0.f);
                    C[(size_t)m * N + n] = (bf16)v;
                }
            }
        }
    }
}

// ---------------- split-K GEMM: partial-buffer stores (NO atomics), bf16 W ----------------
// XCD rect: all gx x-tiles x SY y-tiles x 1 z-slice per XCD ((gy/SY)*gz == 8).
// Each z-slice writes its partial to Cacc + z*M*N; reduction fused into LN.
template<int SPLIT, int SY>
__global__ __launch_bounds__(256)
void gemm8_splitk(const bf16* __restrict__ A, const bf16* __restrict__ Wfull,
                  float* __restrict__ Cacc, int M, int N, int K)
{
    const int gx = gridDim.x, gy = gridDim.y;
    const int l = (blockIdx.z * gy + blockIdx.y) * gx + blockIdx.x;
    const int k = l & 7, j = l >> 3;
    const int yg = gy / SY;
    const int tx = j % gx;
    const int ty = (k % yg) * SY + (j / gx);
    const int tz = k / yg;
    const int m0 = ty * 128, n0 = tx * 128;
    const int Kc = K / SPLIT;
    const bf16* Ab = A + (size_t)tz * Kc;
    const bf16* W = Wfull + (size_t)tz * Kc;
    float* Cz = Cacc + (size_t)tz * M * N;
    G_PROLOGUE(Ab, W)
    G_KLOOP(Kc)
#pragma unroll
    for (int nt = 0; nt < 4; ++nt) {
        int n = n0 + wn * 64 + nt * 16 + r;
#pragma unroll
        for (int mt = 0; mt < 4; ++mt) {
#pragma unroll
            for (int e = 0; e < 4; ++e) {
                int m = m0 + wm * 64 + mt * 16 + quad * 4 + e;
                Cz[(size_t)m * N + n] = acc[mt][nt][e];
            }
        }
    }
}

// ---------------- banded flash attention with MFMA ----------------
__global__ __launch_bounds__(256)
void attn_mfma(const bf16* __restrict__ qkv, const bf16* __restrict__ Vt,
               bf16* __restrict__ o)
{
    __shared__ __align__(16) __bf16 Plds[4][16 * 40];
    const int tid = threadIdx.x, lane = tid & 63, w = tid >> 6;
    const int h = blockIdx.x & 15;
    const int qw = (blockIdx.x >> 4) * 64 + w * 16;
    const int r = lane & 15, quad = lane >> 4;
    __bf16* P = Plds[w];

    bf16x8 qa[2];
    {
        const bf16* qrow = qkv + (size_t)(qw + r) * 3072 + h * 64 + quad * 8;
#pragma unroll
        for (int c = 0; c < 2; ++c) {
            bf16x8 t = *(const bf16x8*)(qrow + c * 32);
#pragma unroll
            for (int j = 0; j < 8; ++j) qa[c][j] = (__bf16)((float)t[j] * 0.125f);
        }
    }

    bf16x8 ones;
#pragma unroll
    for (int j = 0; j < 8; ++j) ones[j] = (__bf16)1.0f;

    f32x4 acc[4];
#pragma unroll
    for (int d = 0; d < 4; ++d) acc[d] = (f32x4){0.f, 0.f, 0.f, 0.f};
    float m_run[4], l_run[4];
#pragma unroll
    for (int e = 0; e < 4; ++e) { m_run[e] = -1e30f; l_run[e] = 0.f; }

    int jmin = qw - (WINDOW - 1); if (jmin < 0) jmin = 0;
    int jmax = qw + 15 + (WINDOW - 1); if (jmax > SEQ - 1) jmax = SEQ - 1;

    for (int kt = jmin & ~31; kt <= jmax; kt += 32) {
        f32x4 S[2];
#pragma unroll
        for (int c = 0; c < 2; ++c) {
            const bf16* krow = qkv + (size_t)(kt + 16 * c + r) * 3072 + 1024 + h * 64 + quad * 8;
            bf16x8 kb0 = *(const bf16x8*)(krow);
            bf16x8 kb1 = *(const bf16x8*)(krow + 32);
            f32x4 s = (f32x4){0.f, 0.f, 0.f, 0.f};
            s = __builtin_amdgcn_mfma_f32_16x16x32_bf16(qa[0], kb0, s, 0, 0, 0);
            s = __builtin_amdgcn_mfma_f32_16x16x32_bf16(qa[1], kb1, s, 0, 0, 0);
            S[c] = s;
        }
#pragma unroll
        for (int c = 0; c < 2; ++c)
#pragma unroll
            for (int e = 0; e < 4; ++e) {
                int j = kt + 16 * c + r;
                int i = qw + quad * 4 + e;
                bool valid = (unsigned)(j - i + (WINDOW - 1)) <= (unsigned)(2 * WINDOW - 2);
                S[c][e] = valid ? S[c][e] : -1e30f;
            }
        float alpha[4], mnew[4];
#pragma unroll
        for (int e = 0; e < 4; ++e) {
            float v = fmaxf(S[0][e], S[1][e]);
#pragma unroll
            for (int off = 1; off <= 8; off <<= 1) v = fmaxf(v, __shfl_xor(v, off, 64));
            mnew[e] = fmaxf(m_run[e], v);
            alpha[e] = __expf(m_run[e] - mnew[e]);
            m_run[e] = mnew[e];
        }
#pragma unroll
        for (int c = 0; c < 2; ++c)
#pragma unroll
            for (int e = 0; e < 4; ++e) {
                float p = __expf(S[c][e] - mnew[e]);
                p = (S[c][e] <= -1e29f) ? 0.f : p;
                P[(quad * 4 + e) * 40 + 16 * c + r] = (__bf16)p;
            }
        bf16x8 pa = *(const bf16x8*)(P + r * 40 + quad * 8);
#pragma unroll
        for (int d = 0; d < 4; ++d)
#pragma unroll
            for (int e = 0; e < 4; ++e) acc[d][e] *= alpha[e];
        f32x4 ls = (f32x4){0.f, 0.f, 0.f, 0.f};
        ls = __builtin_amdgcn_mfma_f32_16x16x32_bf16(pa, ones, ls, 0, 0, 0);
#pragma unroll
        for (int e = 0; e < 4; ++e) l_run[e] = l_run[e] * alpha[e] + ls[e];
#pragma unroll
        for (int d = 0; d < 4; ++d) {
            const bf16* vrow = Vt + (size_t)(h * 64 + 16 * d + r) * SEQ + kt + quad * 8;
            bf16x8 vb = *(const bf16x8*)(vrow);
            acc[d] = __builtin_amdgcn_mfma_f32_16x16x32_bf16(pa, vb, acc[d], 0, 0, 0);
        }
    }

#pragma unroll
    for (int d = 0; d < 4; ++d)
#pragma unroll
        for (int e = 0; e < 4; ++e) {
            int i = qw + quad * 4 + e;
            o[(size_t)i * DMODEL + h * 64 + 16 * d + r] = (bf16)(acc[d][e] / l_run[e]);
        }
}

// ---------------- residual + layernorm, delta = sum of 4 f32 partials + f32 bias ----------------
__global__ __launch_bounds__(256)
void ln_residual_f32(bf16* __restrict__ x, const float* __restrict__ accd,
                     const float* __restrict__ bias,
                     const float* __restrict__ gamma, const float* __restrict__ beta)
{
    const int s = blockIdx.x, tid = threadIdx.x;
    const int lane = tid & 63, wave = tid >> 6;
    __shared__ float red[8];
    float v[4];
    float sum = 0.f;
#pragma unroll
    for (int i = 0; i < 4; ++i) {
        int d = i * 256 + tid;
        float a = accd[(size_t)s * 1024 + d]
                + accd[(size_t)SEQ * 1024 + (size_t)s * 1024 + d]
                + accd[2 * (size_t)SEQ * 1024 + (size_t)s * 1024 + d]
                + accd[3 * (size_t)SEQ * 1024 + (size_t)s * 1024 + d];
        v[i] = (float)x[(size_t)s * 1024 + d] + a + bias[d];
        sum += v[i];
    }
#pragma unroll
    for (int off = 32; off; off >>= 1) sum += __shfl_xor(sum, off, 64);
    if (lane == 0) red[wave] = sum;
    __syncthreads();
    float mu = (red[0] + red[1] + red[2] + red[3]) * (1.f / 1024.f);
    float sq = 0.f;
#pragma unroll
    for (int i = 0; i < 4; ++i) { float t = v[i] - mu; sq += t * t; }
#pragma unroll
    for (int off = 32; off; off >>= 1) sq += __shfl_xor(sq, off, 64);
    if (lane == 0) red[wave + 4] = sq;
    __syncthreads();
    float var = (red[4] + red[5] + red[6] + red[7]) * (1.f / 1024.f);
    float inv = rsqrtf(var + LN_EPS);
#pragma unroll
    for (int i = 0; i < 4; ++i) {
        int d = i * 256 + tid;
        x[(size_t)s * 1024 + d] = (bf16)((v[i] - mu) * inv * gamma[d] + beta[d]);
    }
}

// ---------------- decoder: logits + log_softmax ----------------
__global__ __launch_bounds__(256)
void decoder(const bf16* __restrict__ x, const float* __restrict__ Wdec,
             const float* __restrict__ bdec, float* __restrict__ out)
{
    const int s = blockIdx.x * 4 + (threadIdx.x >> 6);
    const int lane = threadIdx.x & 63;
    float a0 = 0.f, a1 = 0.f, a2 = 0.f;
    for (int d = lane; d < 1024; d += 64) {
        float xv = (float)x[(size_t)s * 1024 + d];
        a0 += xv * Wdec[d];
        a1 += xv * Wdec[1024 + d];
        a2 += xv * Wdec[2048 + d];
    }
#pragma unroll
    for (int off = 32; off; off >>= 1) {
        a0 += __shfl_xor(a0, off, 64);
        a1 += __shfl_xor(a1, off, 64);
        a2 += __shfl_xor(a2, off, 64);
    }
    if (lane == 0) {
        float z0 = a0 + bdec[0];
        float z1 = a1 + bdec[1];
        float z2 = a2 + bdec[2];
        float mx = fmaxf(z0, fmaxf(z1, z2));
        float lse = mx + logf(__expf(z0 - mx) + __expf(z1 - mx) + __expf(z2 - mx));
        out[s * 3 + 0] = z0 - lse;
        out[s * 3 + 1] = z1 - lse;
        out[s * 3 + 2] = z2 - lse;
    }
}

extern "C" void kernel_launch(void* const* d_in, const int* in_sizes, int n_in,
                              void* d_out, int out_size, void* d_ws, size_t ws_size,
                              hipStream_t stream)
{
    const float* X    = (const float*)d_in[0];
    const float* Wqkv = (const float*)d_in[1];
    const float* bqkv = (const float*)d_in[2];
    const float* Wo   = (const float*)d_in[3];
    const float* bo   = (const float*)d_in[4];
    const float* ln1g = (const float*)d_in[5];
    const float* ln1b = (const float*)d_in[6];
    const float* W1   = (const float*)d_in[7];
    const float* b1   = (const float*)d_in[8];
    const float* W2   = (const float*)d_in[9];
    const float* b2   = (const float*)d_in[10];
    const float* ln2g = (const float*)d_in[11];
    const float* ln2b = (const float*)d_in[12];
    const float* Wdec = (const float*)d_in[13];
    const float* bdec = (const float*)d_in[14];

    // workspace (bf16 elems):
    //   x[2M] | buf[8M]=qkv6M/ao2M (reused as h) | Vt[2M]
    //   | accf 4 x 2M f32 split-K partials (32 MB) | Wb[12.583M] per-layer bf16 weights
    bf16* ws   = (bf16*)d_ws;
    bf16* x    = ws;                                  // 2M
    bf16* buf  = x   + (size_t)SEQ * DMODEL;          // 8M
    bf16* qkv  = buf;
    bf16* ao   = buf + (size_t)SEQ * 3 * DMODEL;
    bf16* h    = buf;
    bf16* Vt   = buf + (size_t)SEQ * DFF;             // 2M
    float* accf = (float*)(Vt + (size_t)SEQ * DMODEL);    // 4 x 2M f32 (32 MB)
    bf16* Wb   = (bf16*)(accf + 4 * (size_t)SEQ * DMODEL);
    bf16* WoB  = Wb + 3145728;
    bf16* W1B  = Wb + 4194304;
    bf16* W2B  = Wb + 8388608;

    add_pe<<<(SEQ * DMODEL) / 256, 256, 0, stream>>>(X, x);

    for (int l = 0; l < 4; ++l) {
        // convert this layer's weights f32 -> bf16 (contiguous Wb)
        cvt_w_layer<<<6144, 256, 0, stream>>>(
            Wqkv + (size_t)l * 3145728, Wo + (size_t)l * 1048576,
            W1 + (size_t)l * 4194304,  W2 + (size_t)l * 4194304, Wb);
        // QKV projection; V third written transposed straight into Vt.
        // grid 24x16 = 384 blocks (1.5/CU); XCD rect 6x x 8y (~2.3MB WS).
        gemm8_bt<0, 6, 8, 1><<<dim3(3072 / 128, SEQ / 128), 256, 0, stream>>>(
            x, Wb, bqkv + l * 3072, qkv, Vt, SEQ, 3072, 1024);
        // banded flash attention
        attn_mfma<<<(SEQ / 64) * NHEAD, 256, 0, stream>>>(qkv, Vt, ao);
        // O projection (split-K=4, partial stores; bias folded into LN)
        // grid 8x16x4 = 512 blocks (2/CU); per-XCD 8x x 8y x 1z (~1MB WS).
        gemm8_splitk<4, 8><<<dim3(1024 / 128, SEQ / 128, 4), 256, 0, stream>>>(
            ao, WoB, accf, SEQ, 1024, 1024);
        ln_residual_f32<<<SEQ, 256, 0, stream>>>(x, accf, bo + l * 1024,
                                                 ln1g + l * 1024, ln1b + l * 1024);
        // FF1 (relu, direct) — h overwrites qkv/ao region
        // grid 32x16 = 512 blocks (2/CU); XCD rect 8x x 8y (~4MB WS).
        gemm8_bt<1, 8, 8, 0><<<dim3(4096 / 128, SEQ / 128), 256, 0, stream>>>(
            x, W1B, b1 + l * 4096, h, nullptr, SEQ, 4096, 1024);
        // FF2 (split-K=4, partial stores; bias folded into LN)
        // grid 8x16x4 = 512 blocks (2/CU); per-XCD 8x x 8y x 1z (~4MB WS).
        gemm8_splitk<4, 8><<<dim3(1024 / 128, SEQ / 128, 4), 256, 0, stream>>>(
            h, W2B, accf, SEQ, 1024, 4096);
        ln_residual_f32<<<SEQ, 256, 0, stream>>>(x, accf, b2 + l * 1024,
                                                 ln2g + l * 1024, ln2b + l * 1024);
    }

    decoder<<<SEQ / 4, 256, 0, stream>>>(x, Wdec, bdec, (float*)d_out);
}